// Round 5
// baseline (288.163 us; speedup 1.0000x reference)
//
#include <hip/hip_runtime.h>
#include <hip/hip_bf16.h>

typedef __hip_bfloat16 bf16;
typedef unsigned short u16;
typedef __attribute__((ext_vector_type(8))) short short8;
typedef __attribute__((ext_vector_type(4))) float f32x4;

#define D_MODEL 1024
#define NUM_HEADS 16
#define DEPTH 64
#define BATCH 4
#define SEQ 1024
#define BS (BATCH * SEQ)

__device__ __forceinline__ float ldDyn(const void* p, size_t i, int isbf) {
  return isbf ? __bfloat162float(((const bf16*)p)[i]) : ((const float*)p)[i];
}
__device__ __forceinline__ u16 f2bf(float f) {
  bf16 h = __float2bfloat16(f);
  return *(u16*)&h;
}
// async global->LDS, 16B per lane; LDS dest = wave-uniform base + lane*16
__device__ __forceinline__ void gl2lds16(const void* g, void* l) {
  __builtin_amdgcn_global_load_lds((const __attribute__((address_space(1))) unsigned int*)g,
                                   (__attribute__((address_space(3))) unsigned int*)l, 16, 0, 0);
}

// Per-block dtype detection (deterministic -> every block derives the same
// value; no cross-block ordering needed).
__device__ __forceinline__ int detect_isbf(const u16* q) {
  int sane = 0;
#pragma unroll
  for (int i = 0; i < 64; ++i) {
    int e = (q[2 * i] >> 7) & 0xFF;
    sane += (e >= 100 && e <= 150) ? 1 : 0;
  }
  return (sane >= 48) ? 1 : 0;
}

// Merged prep kernel (detect + convert + weight transpose in one launch).
// z < 4: convert q/k/v/pos to bf16. z in [4,10): transpose weight z-4.
__global__ __launch_bounds__(256) void prep(
    const void* __restrict__ q, const void* __restrict__ k, const void* __restrict__ v,
    const void* __restrict__ pos, const void* __restrict__ W0, const void* __restrict__ W1,
    const void* __restrict__ W2, const void* __restrict__ W3, const void* __restrict__ W4,
    const void* __restrict__ W5, u16* __restrict__ Qb, u16* __restrict__ Kb,
    u16* __restrict__ Vb, u16* __restrict__ Pb, u16* __restrict__ WT,
    int* __restrict__ flag) {
  const int isbf = detect_isbf((const u16*)q);
  const int z = blockIdx.z;
  const int t = threadIdx.x;
  if (z == 0 && blockIdx.x == 0 && t == 0) *flag = isbf;

  if (z < 4) {
    const void* src = (z == 0) ? q : (z == 1) ? k : (z == 2) ? v : pos;
    u16* dst = (z == 0) ? Qb : (z == 1) ? Kb : (z == 2) ? Vb : Pb;
    const size_t n8 = ((z == 3) ? (size_t)SEQ * D_MODEL : (size_t)BS * D_MODEL) / 8;
    for (size_t i = (size_t)blockIdx.x * 256 + t; i < n8; i += (size_t)gridDim.x * 256) {
      short8 o;
      if (isbf) {
        o = ((const short8*)src)[i];
      } else {
        const float4* f = (const float4*)src + 2 * i;
        float4 lo = f[0], hi = f[1];
        u16* pv = (u16*)&o;
        pv[0] = f2bf(lo.x); pv[1] = f2bf(lo.y); pv[2] = f2bf(lo.z); pv[3] = f2bf(lo.w);
        pv[4] = f2bf(hi.x); pv[5] = f2bf(hi.y); pv[6] = f2bf(hi.z); pv[7] = f2bf(hi.w);
      }
      ((short8*)dst)[i] = o;
    }
  } else {
    const int w = z - 4;
    const void* W = (w == 0) ? W0 : (w == 1) ? W1 : (w == 2) ? W2
                   : (w == 3) ? W3 : (w == 4) ? W4 : W5;
    u16* out = WT + (size_t)w * D_MODEL * D_MODEL;
    __shared__ u16 tile[32][33];
    const int tx = t & 31, ty = t >> 5;
    const int r0 = (blockIdx.x >> 5) * 32, c0 = (blockIdx.x & 31) * 32;
#pragma unroll
    for (int i = 0; i < 4; ++i) {
      size_t gi = (size_t)(r0 + ty + 8 * i) * D_MODEL + c0 + tx;
      tile[ty + 8 * i][tx] = isbf ? ((const u16*)W)[gi] : f2bf(((const float*)W)[gi]);
    }
    __syncthreads();
#pragma unroll
    for (int i = 0; i < 4; ++i)
      out[(size_t)(c0 + ty + 8 * i) * D_MODEL + r0 + tx] = tile[tx][ty + 8 * i];
  }
}

struct GArgs {
  const u16* A[5];
  const u16* W[5];
  const void* bias[5];
  void* C[5];
  int Mr[5];
  int om[5];
};

// C(M,1024) = A(M,1024) @ W + bias, W transposed (WT, bf16), A bf16.
// Round-5: arithmetic-intensity move. r2/r4 both hit ~58-59us at very
// different occupancies -> wall is LDS traffic + per-step serialization, set
// by per-wave FLOP/LDS-byte = Mw*Nw/(Mw+Nw). Go to the m201 geometry:
// block 256x256, 8 waves (2 wrow x 4 wcol), per-wave 128x64 (ratio 42.7 vs
// r4's 21): 12 fragment ds_reads feed 32 MFMA per wave-step (2x FLOP/byte),
// total fragment-read traffic halves, staged-DMA traffic halves (fewer
// redundant col/row blocks). Pipeline is the proven 3-buffer counted-vmcnt
// loop: stage k+2 issued at step k (2-step slack covers HBM latency), ONE
// s_waitcnt vmcnt(4)+s_barrier per step (4 DMA/thread/stage, never 0 in
// loop), fully unrolled. LDS 96 KB -> 1 block/CU, 8 waves (the m201
// operating point; all hiding intra-block). setprio(1) around the 32-MFMA
// cluster (T5 -- 2 waves/SIMD alternate stage/MFMA roles).
// omode: 0 = final out (dtype per flag); 1 = bf16; 2 = bf16 transposed [N][M].
__global__ __launch_bounds__(512, 2) void gemm_mfma(GArgs ga, const int* __restrict__ flagp) {
  const int isbf = *flagp;
  const int z = blockIdx.z;
  const int M = ga.Mr[z];
  // XCD swizzle, grid (4,16,z): lin 0..63, assume xcd = lin&7 round-robin.
  // M=4096: XCD x owns row-panels {2x,2x+1} x all 4 col-blocks (A L2-local).
  // M=1024: 16 active blocks spread 2-per-XCD.
  const int lin = blockIdx.x + 4 * blockIdx.y;  // 0..63
  const int xcd = lin & 7;
  const int idx = lin >> 3;                     // 0..7
  int rowb, colb;
  if (M >= 4096) {
    rowb = xcd * 2 + (idx & 1);                 // 0..15
    colb = idx >> 1;                            // 0..3
  } else {
    if (idx >= 2) return;
    rowb = idx * 2 + (xcd & 1);                 // 0..3
    colb = xcd >> 1;                            // 0..3
  }
  const int row0 = rowb * 256, col0 = colb * 256;
  if (row0 >= M) return;
  const u16* A = ga.A[z];
  const u16* WT = ga.W[z];
  const void* bias = ga.bias[z];
  void* C = ga.C[z];
  const int omode = ga.om[z];

  __shared__ short As[3][256][32];  // 48 KB
  __shared__ short Bs[3][256][32];  // 48 KB
  const int t = threadIdx.x;                    // 0..511
  const int wave = t >> 6, lane = t & 63;
  const int quad = lane >> 4, c16 = lane & 15;
  const int wrow = wave >> 2;                   // 0..1 : 128-row strip
  const int wcol = wave & 3;                    // 0..3 : 64-col strip

  f32x4 acc[8][4];
#pragma unroll
  for (int mt = 0; mt < 8; ++mt)
#pragma unroll
    for (int nt = 0; nt < 4; ++nt) acc[mt][nt] = {0.f, 0.f, 0.f, 0.f};

  // Stage one BK=32 tile (A 256x32, B 256x32) into buffer BUF; 4 DMA/thread.
  // Global-side swizzle: LDS slot s of row r holds chunk s ^ f(r),
  // f(r) = (r + (r>>2)) & 3.
#define G_STAGE(K0, BUF)                                                                  \
  {                                                                                       \
    _Pragma("unroll") for (int j = 0; j < 2; ++j) {                                       \
      int L = t + 512 * j;                                                                \
      int r = L >> 2;                                                                     \
      int kc = (L & 3) ^ ((r + (r >> 2)) & 3);                                            \
      gl2lds16(A + (size_t)(row0 + r) * 1024 + (K0) + kc * 8,                             \
               (char*)&As[BUF][0][0] + (size_t)(j * 512 + wave * 64) * 16);               \
      gl2lds16(WT + (size_t)(col0 + r) * 1024 + (K0) + kc * 8,                            \
               (char*)&Bs[BUF][0][0] + (size_t)(j * 512 + wave * 64) * 16);               \
    }                                                                                     \
  }

  const int fsw = (c16 + (c16 >> 2)) & 3;  // = f(row) for row = base16k + c16

#define COMPUTE(BUF)                                                                      \
  {                                                                                       \
    short8 af[8], bfv[4];                                                                 \
    _Pragma("unroll") for (int mt = 0; mt < 8; ++mt)                                      \
        af[mt] = *(const short8*)&As[BUF][wrow * 128 + mt * 16 + c16][((quad ^ fsw) * 8)];\
    _Pragma("unroll") for (int nt = 0; nt < 4; ++nt)                                      \
        bfv[nt] = *(const short8*)&Bs[BUF][wcol * 64 + nt * 16 + c16][((quad ^ fsw) * 8)];\
    __builtin_amdgcn_s_setprio(1);                                                        \
    _Pragma("unroll") for (int nt = 0; nt < 4; ++nt)                                      \
      _Pragma("unroll") for (int mt = 0; mt < 8; ++mt)                                    \
          acc[mt][nt] =                                                                   \
              __builtin_amdgcn_mfma_f32_16x16x32_bf16(af[mt], bfv[nt], acc[mt][nt], 0, 0, 0); \
    __builtin_amdgcn_s_setprio(0);                                                        \
  }

  G_STAGE(0, 0);
  G_STAGE(32, 1);
#pragma unroll
  for (int kk = 0; kk < 31; ++kk) {
    // drain stage kk (stage kk+1's 4 DMA/thread stay in flight), then barrier
    asm volatile("s_waitcnt vmcnt(4)\n\ts_barrier" ::: "memory");
    if (kk < 30) G_STAGE((kk + 2) * 32, (kk + 2) % 3);
    COMPUTE(kk % 3);
  }
  asm volatile("s_waitcnt vmcnt(0)\n\ts_barrier" ::: "memory");
  COMPUTE(1);  // 31 % 3
#undef G_STAGE
#undef COMPUTE

#pragma unroll
  for (int nt = 0; nt < 4; ++nt) {
    int gc = col0 + wcol * 64 + nt * 16 + c16;
    float bb = ldDyn(bias, gc, isbf);
#pragma unroll
    for (int mt = 0; mt < 8; ++mt) {
      int gr0 = row0 + wrow * 128 + mt * 16 + quad * 4;
      if (omode == 2) {
        __attribute__((ext_vector_type(4))) short pk;
#pragma unroll
        for (int r = 0; r < 4; ++r) pk[r] = (short)f2bf(acc[mt][nt][r] + bb);
        *(__attribute__((ext_vector_type(4))) short*)&((u16*)C)[(size_t)gc * M + gr0] = pk;
      } else if (omode == 1 || isbf) {
#pragma unroll
        for (int r = 0; r < 4; ++r)
          ((bf16*)C)[(size_t)(gr0 + r) * 1024 + gc] = __float2bfloat16(acc[mt][nt][r] + bb);
      } else {
#pragma unroll
        for (int r = 0; r < 4; ++r)
          ((float*)C)[(size_t)(gr0 + r) * 1024 + gc] = acc[mt][nt][r] + bb;
      }
    }
  }
}

// Flash attention, m97-style: double-buffered async global_load_lds staging of
// the K-hat (64x128) and V^T (64x64) tiles; one barrier per kt drains the DMA
// (per-kt compute is long enough to cover the DMA latency). s_setprio around
// the MFMA clusters (m191: +4-7% on independent-block attention).
__global__ __launch_bounds__(256) void flash_attn(
    const bf16* __restrict__ Qc, const bf16* __restrict__ Kc, const bf16* __restrict__ VcT,
    const bf16* __restrict__ Qp, const bf16* __restrict__ Kp,
    const void* __restrict__ th_cc, const void* __restrict__ th_co,
    const void* __restrict__ th_oc, bf16* __restrict__ O, const int* __restrict__ flagp) {
  const int isbf = *flagp;
  const int h = blockIdx.x, b = blockIdx.y, qt = blockIdx.z;
  const int t = threadIdx.x, wave = t >> 6, lane = t & 63;
  const int quad = lane >> 4, c16 = lane & 15;

  __shared__ short Kt[2][64][128];  // [buf][key][aug dims], slot kc holds chunk kc^(key&15)
  __shared__ short Vt[2][64][64];   // [buf][d][keys], slot kc holds chunk kc^(d&7)
  __shared__ short Pt[4][16][64];   // per-wave P strip (mt-sequential), swizzled ^ (row&7)

  const float tcc = ldDyn(th_cc, h, isbf);
  const float tco = ldDyn(th_co, h, isbf);
  const float toc = ldDyn(th_oc, h, isbf);

  const bf16* kcb = Kc + (size_t)b * SEQ * 1024 + h * 64;
  const bf16* kpb = Kp + h * 64;
  const bf16* vtb = VcT + (size_t)(h * 64) * BS + (size_t)b * SEQ;

  // staging lane roles
  const int rwK = lane >> 4, kcK = lane & 15;  // K-hat: 4 rows/inst, 16 chunks/row
  const int rwV = lane >> 3, kcV = lane & 7;   // V^T : 8 rows/inst,  8 chunks/row

#define STAGE_K(KT2, BUF)                                                              \
  {                                                                                    \
    _Pragma("unroll") for (int i = 0; i < 4; ++i) {                                    \
      int r = wave * 16 + i * 4 + rwK;                                                 \
      int c = kcK ^ (r & 15);                                                          \
      int key = (KT2)*64 + r;                                                          \
      const bf16* src = (c < 8) ? kcb + (size_t)key * 1024 + c * 8                     \
                                : kpb + (size_t)key * 1024 + c * 8 - 64;               \
      gl2lds16(src, &Kt[BUF][wave * 16 + i * 4][0]);                                   \
    }                                                                                  \
  }
#define STAGE_V(KT2, BUF)                                                              \
  {                                                                                    \
    _Pragma("unroll") for (int j = 0; j < 2; ++j) {                                    \
      int d = wave * 16 + j * 8 + rwV;                                                 \
      int c = kcV ^ (d & 7);                                                           \
      gl2lds16(vtb + (size_t)d * BS + (KT2)*64 + c * 8, &Vt[BUF][wave * 16 + j * 8][0]); \
    }                                                                                  \
  }

  // Q A-frags (register-resident, 2 strips)
  short8 qf[2][4];
#pragma unroll
  for (int mt = 0; mt < 2; ++mt) {
    int qrow = qt * 128 + wave * 32 + mt * 16 + c16;
#pragma unroll
    for (int ks = 0; ks < 4; ++ks) {
      int d = ks * 32 + quad * 8;
      const bf16* src = (d < 64) ? Qc + ((size_t)(b * SEQ + qrow)) * 1024 + h * 64 + d
                                 : Qp + (size_t)qrow * 1024 + h * 64 + (d - 64);
      qf[mt][ks] = *(const short8*)src;
    }
    if (qrow == 0) {  // zero pos-half for q==0 (theta replaces pos there)
      qf[mt][2] = (short8)0;
      qf[mt][3] = (short8)0;
    }
  }

  f32x4 accO[2][4];
#pragma unroll
  for (int mt = 0; mt < 2; ++mt)
#pragma unroll
    for (int nt = 0; nt < 4; ++nt) accO[mt][nt] = {0.f, 0.f, 0.f, 0.f};
  float lrow[2][4] = {{0.f, 0.f, 0.f, 0.f}, {0.f, 0.f, 0.f, 0.f}};

  // prologue: stage tile 0, drain, zero key-0 pos-half (theta replaces it)
  STAGE_K(0, 0);
  STAGE_V(0, 0);
  __syncthreads();
  if (t < 8) *(short8*)&Kt[0][0][64 + t * 8] = (short8)0;  // row0 swizzle = identity
  __syncthreads();

  for (int kt = 0; kt < 16; ++kt) {
    const int cur = kt & 1, nxt = cur ^ 1;
    if (kt < 15) {
      STAGE_K(kt + 1, nxt);
      STAGE_V(kt + 1, nxt);
    }

    // ---- S = Q-hat (32x128) x K-hat^T from LDS ----
    f32x4 accS[2][4];
#pragma unroll
    for (int mt = 0; mt < 2; ++mt)
#pragma unroll
      for (int nt = 0; nt < 4; ++nt) accS[mt][nt] = {0.f, 0.f, 0.f, 0.f};
    __builtin_amdgcn_s_setprio(1);
#pragma unroll
    for (int nt = 0; nt < 4; ++nt)
#pragma unroll
      for (int ks = 0; ks < 4; ++ks) {
        short8 kf = *(const short8*)&Kt[cur][nt * 16 + c16][((ks * 4 + quad) ^ c16) * 8];
#pragma unroll
        for (int mt = 0; mt < 2; ++mt)
          accS[mt][nt] = __builtin_amdgcn_mfma_f32_16x16x32_bf16(qf[mt][ks], kf, accS[mt][nt], 0, 0, 0);
      }
    __builtin_amdgcn_s_setprio(0);

    // ---- V frags to registers (reused by both strips) ----
    short8 vbreg[2][4];
#pragma unroll
    for (int ks2 = 0; ks2 < 2; ++ks2)
#pragma unroll
      for (int nt = 0; nt < 4; ++nt)
        vbreg[ks2][nt] =
            *(const short8*)&Vt[cur][nt * 16 + c16][(((ks2 * 4 + quad) ^ (c16 & 7)) & 7) * 8];

    // ---- per strip: softmax-lite + P roundtrip + PV ----
#pragma unroll
    for (int mt = 0; mt < 2; ++mt) {
      float s[4][4];
#pragma unroll
      for (int nt = 0; nt < 4; ++nt)
#pragma unroll
        for (int r = 0; r < 4; ++r) s[nt][r] = accS[mt][nt][r] * 0.125f;

      if (kt == 0 || (qt == 0 && wave == 0 && mt == 0)) {
#pragma unroll
        for (int nt = 0; nt < 4; ++nt)
#pragma unroll
          for (int r = 0; r < 4; ++r) {
            int kcol = kt * 64 + nt * 16 + c16;
            int qrow = qt * 128 + wave * 32 + mt * 16 + quad * 4 + r;
            float add = 0.f;
            if (qrow == 0 && kcol == 0) add = tcc;
            else if (qrow == 0) add = tco;
            else if (kcol == 0) add = toc;
            s[nt][r] += add * 0.125f;
          }
      }
#pragma unroll
      for (int nt = 0; nt < 4; ++nt)
#pragma unroll
        for (int r = 0; r < 4; ++r) {
          float p = __expf(s[nt][r]);
          lrow[mt][r] += p;
          int row = quad * 4 + r;
          int ch = nt * 2 + (c16 >> 3);
          Pt[wave][row][((ch ^ (row & 7)) * 8) + (c16 & 7)] = (short)f2bf(p);
        }
      __builtin_amdgcn_s_setprio(1);
#pragma unroll
      for (int ks2 = 0; ks2 < 2; ++ks2) {
        short8 pf = *(const short8*)&Pt[wave][c16][(((ks2 * 4 + quad) ^ (c16 & 7)) & 7) * 8];
#pragma unroll
        for (int nt = 0; nt < 4; ++nt)
          accO[mt][nt] = __builtin_amdgcn_mfma_f32_16x16x32_bf16(pf, vbreg[ks2][nt], accO[mt][nt], 0, 0, 0);
      }
      __builtin_amdgcn_s_setprio(0);
    }
    __syncthreads();  // drains next-tile DMA; protects buffer reuse
  }

  // one deferred l-reduction across the 16 c16 lanes
#pragma unroll
  for (int d = 1; d < 16; d <<= 1)
#pragma unroll
    for (int mt = 0; mt < 2; ++mt)
#pragma unroll
      for (int r = 0; r < 4; ++r) lrow[mt][r] += __shfl_xor(lrow[mt][r], d, 64);

#pragma unroll
  for (int mt = 0; mt < 2; ++mt)
#pragma unroll
    for (int nt = 0; nt < 4; ++nt)
#pragma unroll
      for (int r = 0; r < 4; ++r) {
        int qrow = qt * 128 + wave * 32 + mt * 16 + quad * 4 + r;
        O[((size_t)(b * SEQ + qrow)) * 1024 + h * 64 + nt * 16 + c16] =
            __float2bfloat16(accO[mt][nt][r] / lrow[mt][r]);
      }
#undef STAGE_K
#undef STAGE_V
}

extern "C" void kernel_launch(void* const* d_in, const int* in_sizes, int n_in,
                              void* d_out, int out_size, void* d_ws, size_t ws_size,
                              hipStream_t stream) {
  const void* q = d_in[0];
  const void* k = d_in[1];
  const void* v = d_in[2];
  const void* Wq = d_in[3];
  const void* bq = d_in[4];
  const void* Wk = d_in[5];
  const void* bk = d_in[6];
  const void* Wv = d_in[7];
  const void* bv = d_in[8];
  const void* Uq = d_in[9];
  const void* buq = d_in[10];
  const void* Uk = d_in[11];
  const void* buk = d_in[12];
  const void* pos = d_in[13];
  const void* th_cc = d_in[14];
  const void* th_co = d_in[15];
  const void* th_oc = d_in[16];
  const void* Wo = d_in[17];
  const void* bo = d_in[18];

  const int M = BS;  // 4096
  const size_t DD = (size_t)D_MODEL * D_MODEL;
  char* wsb = (char*)d_ws;
  int* flag = (int*)wsb;
  bf16* Qc = (bf16*)(wsb + 256);            // 8 MB
  bf16* Kc = Qc + (size_t)M * D_MODEL;      // 8 MB
  bf16* VcT = Kc + (size_t)M * D_MODEL;     // 8 MB, [D_MODEL][M]
  bf16* Qp = VcT + (size_t)M * D_MODEL;     // 2 MB
  bf16* Kp = Qp + (size_t)SEQ * D_MODEL;    // 2 MB
  u16* WT = (u16*)(Kp + (size_t)SEQ * D_MODEL);  // 6 x 2 MB
  bf16* AO = (bf16*)WT;  // aliases WqT..UqT (dead after g1); WoT (slot 5) untouched
  u16* Qb = WT + 6 * DD;                    // 8 MB bf16 copies of activations
  u16* Kb = Qb + (size_t)M * D_MODEL;       // 8 MB
  u16* Vb = Kb + (size_t)M * D_MODEL;       // 8 MB
  u16* Pb = Vb + (size_t)M * D_MODEL;       // 2 MB (first SEQ rows of pos_table)

  prep<<<dim3(1024, 1, 10), dim3(256), 0, stream>>>(q, k, v, pos, Wq, Wk, Wv, Uq, Uk, Wo,
                                                    Qb, Kb, Vb, Pb, WT, flag);

  GArgs g1 = {{Qb, Kb, Vb, Pb, Pb},
              {WT + 0 * DD, WT + 1 * DD, WT + 2 * DD, WT + 3 * DD, WT + 4 * DD},
              {bq, bk, bv, buq, buk},
              {Qc, Kc, VcT, Qp, Kp},
              {M, M, M, SEQ, SEQ},
              {1, 1, 2, 1, 1}};
  gemm_mfma<<<dim3(4, 16, 5), dim3(512), 0, stream>>>(g1, flag);

  flash_attn<<<dim3(NUM_HEADS, BATCH, SEQ / 128), dim3(256), 0, stream>>>(
      Qc, Kc, VcT, Qp, Kp, th_cc, th_co, th_oc, AO, flag);

  GArgs g2 = {{(const u16*)AO, (const u16*)AO, (const u16*)AO, (const u16*)AO, (const u16*)AO},
              {WT + 5 * DD, WT + 5 * DD, WT + 5 * DD, WT + 5 * DD, WT + 5 * DD},
              {bo, bo, bo, bo, bo},
              {d_out, d_out, d_out, d_out, d_out},
              {M, M, M, M, M},
              {0, 0, 0, 0, 0}};
  gemm_mfma<<<dim3(4, 16, 1), dim3(512), 0, stream>>>(g2, flag);
}

// Round 6
// 272.225 us; speedup vs baseline: 1.0585x; 1.0585x over previous
//
#include <hip/hip_runtime.h>
#include <hip/hip_bf16.h>

typedef __hip_bfloat16 bf16;
typedef unsigned short u16;
typedef __attribute__((ext_vector_type(8))) short short8;
typedef __attribute__((ext_vector_type(4))) float f32x4;

#define D_MODEL 1024
#define NUM_HEADS 16
#define DEPTH 64
#define BATCH 4
#define SEQ 1024
#define BS (BATCH * SEQ)

__device__ __forceinline__ float ldDyn(const void* p, size_t i, int isbf) {
  return isbf ? __bfloat162float(((const bf16*)p)[i]) : ((const float*)p)[i];
}
__device__ __forceinline__ u16 f2bf(float f) {
  bf16 h = __float2bfloat16(f);
  return *(u16*)&h;
}
// async global->LDS, 16B per lane; LDS dest = wave-uniform base + lane*16
__device__ __forceinline__ void gl2lds16(const void* g, void* l) {
  __builtin_amdgcn_global_load_lds((const __attribute__((address_space(1))) unsigned int*)g,
                                   (__attribute__((address_space(3))) unsigned int*)l, 16, 0, 0);
}

// Per-block dtype detection (deterministic -> every block derives the same
// value; no cross-block ordering needed).
__device__ __forceinline__ int detect_isbf(const u16* q) {
  int sane = 0;
#pragma unroll
  for (int i = 0; i < 64; ++i) {
    int e = (q[2 * i] >> 7) & 0xFF;
    sane += (e >= 100 && e <= 150) ? 1 : 0;
  }
  return (sane >= 48) ? 1 : 0;
}

// Merged prep kernel (detect + convert + weight transpose in one launch).
// z < 4: convert q/k/v/pos to bf16. z in [4,10): transpose weight z-4.
__global__ __launch_bounds__(256) void prep(
    const void* __restrict__ q, const void* __restrict__ k, const void* __restrict__ v,
    const void* __restrict__ pos, const void* __restrict__ W0, const void* __restrict__ W1,
    const void* __restrict__ W2, const void* __restrict__ W3, const void* __restrict__ W4,
    const void* __restrict__ W5, u16* __restrict__ Qb, u16* __restrict__ Kb,
    u16* __restrict__ Vb, u16* __restrict__ Pb, u16* __restrict__ WT,
    int* __restrict__ flag) {
  const int isbf = detect_isbf((const u16*)q);
  const int z = blockIdx.z;
  const int t = threadIdx.x;
  if (z == 0 && blockIdx.x == 0 && t == 0) *flag = isbf;

  if (z < 4) {
    const void* src = (z == 0) ? q : (z == 1) ? k : (z == 2) ? v : pos;
    u16* dst = (z == 0) ? Qb : (z == 1) ? Kb : (z == 2) ? Vb : Pb;
    const size_t n8 = ((z == 3) ? (size_t)SEQ * D_MODEL : (size_t)BS * D_MODEL) / 8;
    for (size_t i = (size_t)blockIdx.x * 256 + t; i < n8; i += (size_t)gridDim.x * 256) {
      short8 o;
      if (isbf) {
        o = ((const short8*)src)[i];
      } else {
        const float4* f = (const float4*)src + 2 * i;
        float4 lo = f[0], hi = f[1];
        u16* pv = (u16*)&o;
        pv[0] = f2bf(lo.x); pv[1] = f2bf(lo.y); pv[2] = f2bf(lo.z); pv[3] = f2bf(lo.w);
        pv[4] = f2bf(hi.x); pv[5] = f2bf(hi.y); pv[6] = f2bf(hi.z); pv[7] = f2bf(hi.w);
      }
      ((short8*)dst)[i] = o;
    }
  } else {
    const int w = z - 4;
    const void* W = (w == 0) ? W0 : (w == 1) ? W1 : (w == 2) ? W2
                   : (w == 3) ? W3 : (w == 4) ? W4 : W5;
    u16* out = WT + (size_t)w * D_MODEL * D_MODEL;
    __shared__ u16 tile[32][33];
    const int tx = t & 31, ty = t >> 5;
    const int r0 = (blockIdx.x >> 5) * 32, c0 = (blockIdx.x & 31) * 32;
#pragma unroll
    for (int i = 0; i < 4; ++i) {
      size_t gi = (size_t)(r0 + ty + 8 * i) * D_MODEL + c0 + tx;
      tile[ty + 8 * i][tx] = isbf ? ((const u16*)W)[gi] : f2bf(((const float*)W)[gi]);
    }
    __syncthreads();
#pragma unroll
    for (int i = 0; i < 4; ++i)
      out[(size_t)(c0 + ty + 8 * i) * D_MODEL + r0 + tx] = tile[tx][ty + 8 * i];
  }
}

struct GArgs {
  const u16* A[5];
  const u16* W[5];
  const void* bias[5];
  void* C[5];
  int Mr[5];
  int om[5];
};

// ---------------- g1 kernel: 256x256 tile, 8 waves, split-step ----------------
// r5 measured 594 TF = the m233 2-phase ceiling (607). This version splits each
// BK=32 step into TWO barrier-separated sub-phases:
//   ph1: stage A-half(k+2) || ds_read bfv[4]+af[0..3] -> 16 MFMA
//   barrier
//   ph2: stage B-half(k+2) || ds_read af[4..7]        -> 16 MFMA
// The mid barrier creates the {MFMA vs load-issue} wave role-split that lets
// setprio arbitrate (m218b mechanism). Counted vmcnt(4) boundary unchanged
// (2+2 stage issues per step, never drained to 0 in the loop).
__global__ __launch_bounds__(512, 2) void gemm_big(GArgs ga, const int* __restrict__ flagp) {
  const int isbf = *flagp;
  const int z = blockIdx.z;
  const int M = ga.Mr[z];
  const int lin = blockIdx.x + 4 * blockIdx.y;  // 0..63
  const int xcd = lin & 7;
  const int idx = lin >> 3;                     // 0..7
  int rowb, colb;
  if (M >= 4096) {
    rowb = xcd * 2 + (idx & 1);                 // 0..15
    colb = idx >> 1;                            // 0..3
  } else {
    if (idx >= 2) return;
    rowb = idx * 2 + (xcd & 1);                 // 0..3
    colb = xcd >> 1;                            // 0..3
  }
  const int row0 = rowb * 256, col0 = colb * 256;
  if (row0 >= M) return;
  const u16* A = ga.A[z];
  const u16* WT = ga.W[z];
  const void* bias = ga.bias[z];
  void* C = ga.C[z];
  const int omode = ga.om[z];

  __shared__ short As[3][256][32];  // 48 KB
  __shared__ short Bs[3][256][32];  // 48 KB
  const int t = threadIdx.x;                    // 0..511
  const int wave = t >> 6, lane = t & 63;
  const int quad = lane >> 4, c16 = lane & 15;
  const int wrow = wave >> 2;                   // 0..1 : 128-row strip
  const int wcol = wave & 3;                    // 0..3 : 64-col strip

  f32x4 acc[8][4];
#pragma unroll
  for (int mt = 0; mt < 8; ++mt)
#pragma unroll
    for (int nt = 0; nt < 4; ++nt) acc[mt][nt] = {0.f, 0.f, 0.f, 0.f};

  // Global-side swizzle: LDS slot s of row r holds chunk s ^ f(r),
  // f(r) = (r + (r>>2)) & 3. 2 gloads per macro (A-only / B-only halves).
#define STAGE_A(K0, BUF)                                                                  \
  {                                                                                       \
    _Pragma("unroll") for (int j = 0; j < 2; ++j) {                                       \
      int L = t + 512 * j;                                                                \
      int r = L >> 2;                                                                     \
      int kc = (L & 3) ^ ((r + (r >> 2)) & 3);                                            \
      gl2lds16(A + (size_t)(row0 + r) * 1024 + (K0) + kc * 8,                             \
               (char*)&As[BUF][0][0] + (size_t)(j * 512 + wave * 64) * 16);               \
    }                                                                                     \
  }
#define STAGE_B(K0, BUF)                                                                  \
  {                                                                                       \
    _Pragma("unroll") for (int j = 0; j < 2; ++j) {                                       \
      int L = t + 512 * j;                                                                \
      int r = L >> 2;                                                                     \
      int kc = (L & 3) ^ ((r + (r >> 2)) & 3);                                            \
      gl2lds16(WT + (size_t)(col0 + r) * 1024 + (K0) + kc * 8,                            \
               (char*)&Bs[BUF][0][0] + (size_t)(j * 512 + wave * 64) * 16);               \
    }                                                                                     \
  }

  const int fsw = (c16 + (c16 >> 2)) & 3;  // = f(row) for row = base16k + c16

  // Prologue: stage tiles 0 and 1 fully.
  STAGE_A(0, 0);
  STAGE_B(0, 0);
  STAGE_A(32, 1);
  STAGE_B(32, 1);
#pragma unroll
  for (int kk = 0; kk < 31; ++kk) {
    const int cur = kk % 3;
    const int pre = (kk + 2) % 3;
    // boundary: stage kk landed (stage kk+1's 4 loads stay in flight)
    asm volatile("s_waitcnt vmcnt(4)\n\ts_barrier" ::: "memory");

    short8 bfv[4], afl[4], afh[4];
    // ---- sub-phase 1: stage A(k+2) || read bfv + af-low -> 16 MFMA ----
    if (kk < 30) STAGE_A((kk + 2) * 32, pre);
#pragma unroll
    for (int nt = 0; nt < 4; ++nt)
      bfv[nt] = *(const short8*)&Bs[cur][wcol * 64 + nt * 16 + c16][((quad ^ fsw) * 8)];
#pragma unroll
    for (int mt = 0; mt < 4; ++mt)
      afl[mt] = *(const short8*)&As[cur][wrow * 128 + mt * 16 + c16][((quad ^ fsw) * 8)];
    __builtin_amdgcn_s_setprio(1);
#pragma unroll
    for (int nt = 0; nt < 4; ++nt)
#pragma unroll
      for (int mt = 0; mt < 4; ++mt)
        acc[mt][nt] = __builtin_amdgcn_mfma_f32_16x16x32_bf16(afl[mt], bfv[nt], acc[mt][nt], 0, 0, 0);
    __builtin_amdgcn_s_setprio(0);

    asm volatile("s_barrier" ::: "memory");  // role-split boundary

    // ---- sub-phase 2: stage B(k+2) || read af-high -> 16 MFMA ----
    if (kk < 30) STAGE_B((kk + 2) * 32, pre);
#pragma unroll
    for (int mt = 0; mt < 4; ++mt)
      afh[mt] = *(const short8*)&As[cur][wrow * 128 + 64 + mt * 16 + c16][((quad ^ fsw) * 8)];
    __builtin_amdgcn_s_setprio(1);
#pragma unroll
    for (int nt = 0; nt < 4; ++nt)
#pragma unroll
      for (int mt = 0; mt < 4; ++mt)
        acc[mt + 4][nt] = __builtin_amdgcn_mfma_f32_16x16x32_bf16(afh[mt], bfv[nt], acc[mt + 4][nt], 0, 0, 0);
    __builtin_amdgcn_s_setprio(0);
  }
  // tail: step 31 (buf 1), everything resident
  asm volatile("s_waitcnt vmcnt(0)\n\ts_barrier" ::: "memory");
  {
    short8 bfv[4], af[8];
#pragma unroll
    for (int nt = 0; nt < 4; ++nt)
      bfv[nt] = *(const short8*)&Bs[1][wcol * 64 + nt * 16 + c16][((quad ^ fsw) * 8)];
#pragma unroll
    for (int mt = 0; mt < 8; ++mt)
      af[mt] = *(const short8*)&As[1][wrow * 128 + mt * 16 + c16][((quad ^ fsw) * 8)];
#pragma unroll
    for (int nt = 0; nt < 4; ++nt)
#pragma unroll
      for (int mt = 0; mt < 8; ++mt)
        acc[mt][nt] = __builtin_amdgcn_mfma_f32_16x16x32_bf16(af[mt], bfv[nt], acc[mt][nt], 0, 0, 0);
  }
#undef STAGE_A
#undef STAGE_B

#pragma unroll
  for (int nt = 0; nt < 4; ++nt) {
    int gc = col0 + wcol * 64 + nt * 16 + c16;
    float bb = ldDyn(bias, gc, isbf);
#pragma unroll
    for (int mt = 0; mt < 8; ++mt) {
      int gr0 = row0 + wrow * 128 + mt * 16 + quad * 4;
      if (omode == 2) {
        __attribute__((ext_vector_type(4))) short pk;
#pragma unroll
        for (int r = 0; r < 4; ++r) pk[r] = (short)f2bf(acc[mt][nt][r] + bb);
        *(__attribute__((ext_vector_type(4))) short*)&((u16*)C)[(size_t)gc * M + gr0] = pk;
      } else if (omode == 1 || isbf) {
#pragma unroll
        for (int r = 0; r < 4; ++r)
          ((bf16*)C)[(size_t)(gr0 + r) * 1024 + gc] = __float2bfloat16(acc[mt][nt][r] + bb);
      } else {
#pragma unroll
        for (int r = 0; r < 4; ++r)
          ((float*)C)[(size_t)(gr0 + r) * 1024 + gc] = acc[mt][nt][r] + bb;
      }
    }
  }
}

// ---------------- g2 kernel: 128x128 tile, 8 waves (round-4 structure) --------
// g2 is a single z-slice: the 256^2 tile left 3/4 of the chip idle (64 blocks).
// This 128^2 config gives 256 blocks, ~3 blocks/CU, 40 VGPR -- r4-proven.
__global__ __launch_bounds__(512) void gemm_128(GArgs ga, const int* __restrict__ flagp) {
  const int isbf = *flagp;
  const int z = blockIdx.z;
  const int M = ga.Mr[z];
  const int lin = blockIdx.x + 8 * blockIdx.y;  // 0..255
  const int xcd = lin & 7;
  const int loc = lin >> 3;                     // 0..31
  const int rowb = (loc & 3) * 8 + xcd;         // 0..31
  const int colb = loc >> 2;                    // 0..7
  const int row0 = rowb * 128, col0 = colb * 128;
  if (row0 >= M) return;
  const u16* A = ga.A[z];
  const u16* WT = ga.W[z];
  const void* bias = ga.bias[z];
  void* C = ga.C[z];
  const int omode = ga.om[z];

  __shared__ short As[3][128][32];  // 24 KB
  __shared__ short Bs[3][128][32];  // 24 KB
  const int t = threadIdx.x;                    // 0..511
  const int wave = t >> 6, lane = t & 63;
  const int quad = lane >> 4, c16 = lane & 15;
  const int wrow = wave >> 2;                   // 0..1 : 64-row strip
  const int wcol = wave & 3;                    // 0..3 : 32-col strip

  f32x4 acc[4][2];
#pragma unroll
  for (int mt = 0; mt < 4; ++mt)
#pragma unroll
    for (int nt = 0; nt < 2; ++nt) acc[mt][nt] = {0.f, 0.f, 0.f, 0.f};

#define G_STAGE(K0, BUF)                                                                  \
  {                                                                                       \
    int r = t >> 2;                                                                       \
    int kc = (t & 3) ^ ((r + (r >> 2)) & 3);                                              \
    gl2lds16(A + (size_t)(row0 + r) * 1024 + (K0) + kc * 8,                               \
             (char*)&As[BUF][0][0] + (size_t)(wave * 64) * 16);                           \
    gl2lds16(WT + (size_t)(col0 + r) * 1024 + (K0) + kc * 8,                              \
             (char*)&Bs[BUF][0][0] + (size_t)(wave * 64) * 16);                           \
  }

  const int fsw = (c16 + (c16 >> 2)) & 3;

#define COMPUTE(BUF)                                                                      \
  {                                                                                       \
    short8 af[4], bfv[2];                                                                 \
    _Pragma("unroll") for (int mt = 0; mt < 4; ++mt)                                      \
        af[mt] = *(const short8*)&As[BUF][wrow * 64 + mt * 16 + c16][((quad ^ fsw) * 8)]; \
    _Pragma("unroll") for (int nt = 0; nt < 2; ++nt)                                      \
        bfv[nt] = *(const short8*)&Bs[BUF][wcol * 32 + nt * 16 + c16][((quad ^ fsw) * 8)];\
    _Pragma("unroll") for (int nt = 0; nt < 2; ++nt)                                      \
      _Pragma("unroll") for (int mt = 0; mt < 4; ++mt)                                    \
          acc[mt][nt] =                                                                   \
              __builtin_amdgcn_mfma_f32_16x16x32_bf16(af[mt], bfv[nt], acc[mt][nt], 0, 0, 0); \
  }

  G_STAGE(0, 0);
  G_STAGE(32, 1);
#pragma unroll
  for (int kk = 0; kk < 31; ++kk) {
    asm volatile("s_waitcnt vmcnt(2)\n\ts_barrier" ::: "memory");
    if (kk < 30) G_STAGE((kk + 2) * 32, (kk + 2) % 3);
    COMPUTE(kk % 3);
  }
  asm volatile("s_waitcnt vmcnt(0)\n\ts_barrier" ::: "memory");
  COMPUTE(1);  // 31 % 3
#undef G_STAGE
#undef COMPUTE

#pragma unroll
  for (int nt = 0; nt < 2; ++nt) {
    int gc = col0 + wcol * 32 + nt * 16 + c16;
    float bb = ldDyn(bias, gc, isbf);
#pragma unroll
    for (int mt = 0; mt < 4; ++mt) {
      int gr0 = row0 + wrow * 64 + mt * 16 + quad * 4;
      if (omode == 2) {
        __attribute__((ext_vector_type(4))) short pk;
#pragma unroll
        for (int r = 0; r < 4; ++r) pk[r] = (short)f2bf(acc[mt][nt][r] + bb);
        *(__attribute__((ext_vector_type(4))) short*)&((u16*)C)[(size_t)gc * M + gr0] = pk;
      } else if (omode == 1 || isbf) {
#pragma unroll
        for (int r = 0; r < 4; ++r)
          ((bf16*)C)[(size_t)(gr0 + r) * 1024 + gc] = __float2bfloat16(acc[mt][nt][r] + bb);
      } else {
#pragma unroll
        for (int r = 0; r < 4; ++r)
          ((float*)C)[(size_t)(gr0 + r) * 1024 + gc] = acc[mt][nt][r] + bb;
      }
    }
  }
}

// Flash attention, m97-style: double-buffered async global_load_lds staging of
// the K-hat (64x128) and V^T (64x64) tiles; one barrier per kt drains the DMA
// (per-kt compute is long enough to cover the DMA latency). s_setprio around
// the MFMA clusters (m191: +4-7% on independent-block attention).
__global__ __launch_bounds__(256) void flash_attn(
    const bf16* __restrict__ Qc, const bf16* __restrict__ Kc, const bf16* __restrict__ VcT,
    const bf16* __restrict__ Qp, const bf16* __restrict__ Kp,
    const void* __restrict__ th_cc, const void* __restrict__ th_co,
    const void* __restrict__ th_oc, bf16* __restrict__ O, const int* __restrict__ flagp) {
  const int isbf = *flagp;
  const int h = blockIdx.x, b = blockIdx.y, qt = blockIdx.z;
  const int t = threadIdx.x, wave = t >> 6, lane = t & 63;
  const int quad = lane >> 4, c16 = lane & 15;

  __shared__ short Kt[2][64][128];  // [buf][key][aug dims], slot kc holds chunk kc^(key&15)
  __shared__ short Vt[2][64][64];   // [buf][d][keys], slot kc holds chunk kc^(d&7)
  __shared__ short Pt[4][16][64];   // per-wave P strip (mt-sequential), swizzled ^ (row&7)

  const float tcc = ldDyn(th_cc, h, isbf);
  const float tco = ldDyn(th_co, h, isbf);
  const float toc = ldDyn(th_oc, h, isbf);

  const bf16* kcb = Kc + (size_t)b * SEQ * 1024 + h * 64;
  const bf16* kpb = Kp + h * 64;
  const bf16* vtb = VcT + (size_t)(h * 64) * BS + (size_t)b * SEQ;

  // staging lane roles
  const int rwK = lane >> 4, kcK = lane & 15;  // K-hat: 4 rows/inst, 16 chunks/row
  const int rwV = lane >> 3, kcV = lane & 7;   // V^T : 8 rows/inst,  8 chunks/row

#define STAGE_K(KT2, BUF)                                                              \
  {                                                                                    \
    _Pragma("unroll") for (int i = 0; i < 4; ++i) {                                    \
      int r = wave * 16 + i * 4 + rwK;                                                 \
      int c = kcK ^ (r & 15);                                                          \
      int key = (KT2)*64 + r;                                                          \
      const bf16* src = (c < 8) ? kcb + (size_t)key * 1024 + c * 8                     \
                                : kpb + (size_t)key * 1024 + c * 8 - 64;               \
      gl2lds16(src, &Kt[BUF][wave * 16 + i * 4][0]);                                   \
    }                                                                                  \
  }
#define STAGE_V(KT2, BUF)                                                              \
  {                                                                                    \
    _Pragma("unroll") for (int j = 0; j < 2; ++j) {                                    \
      int d = wave * 16 + j * 8 + rwV;                                                 \
      int c = kcV ^ (d & 7);                                                           \
      gl2lds16(vtb + (size_t)d * BS + (KT2)*64 + c * 8, &Vt[BUF][wave * 16 + j * 8][0]); \
    }                                                                                  \
  }

  // Q A-frags (register-resident, 2 strips)
  short8 qf[2][4];
#pragma unroll
  for (int mt = 0; mt < 2; ++mt) {
    int qrow = qt * 128 + wave * 32 + mt * 16 + c16;
#pragma unroll
    for (int ks = 0; ks < 4; ++ks) {
      int d = ks * 32 + quad * 8;
      const bf16* src = (d < 64) ? Qc + ((size_t)(b * SEQ + qrow)) * 1024 + h * 64 + d
                                 : Qp + (size_t)qrow * 1024 + h * 64 + (d - 64);
      qf[mt][ks] = *(const short8*)src;
    }
    if (qrow == 0) {  // zero pos-half for q==0 (theta replaces pos there)
      qf[mt][2] = (short8)0;
      qf[mt][3] = (short8)0;
    }
  }

  f32x4 accO[2][4];
#pragma unroll
  for (int mt = 0; mt < 2; ++mt)
#pragma unroll
    for (int nt = 0; nt < 4; ++nt) accO[mt][nt] = {0.f, 0.f, 0.f, 0.f};
  float lrow[2][4] = {{0.f, 0.f, 0.f, 0.f}, {0.f, 0.f, 0.f, 0.f}};

  // prologue: stage tile 0, drain, zero key-0 pos-half (theta replaces it)
  STAGE_K(0, 0);
  STAGE_V(0, 0);
  __syncthreads();
  if (t < 8) *(short8*)&Kt[0][0][64 + t * 8] = (short8)0;  // row0 swizzle = identity
  __syncthreads();

  for (int kt = 0; kt < 16; ++kt) {
    const int cur = kt & 1, nxt = cur ^ 1;
    if (kt < 15) {
      STAGE_K(kt + 1, nxt);
      STAGE_V(kt + 1, nxt);
    }

    // ---- S = Q-hat (32x128) x K-hat^T from LDS ----
    f32x4 accS[2][4];
#pragma unroll
    for (int mt = 0; mt < 2; ++mt)
#pragma unroll
      for (int nt = 0; nt < 4; ++nt) accS[mt][nt] = {0.f, 0.f, 0.f, 0.f};
    __builtin_amdgcn_s_setprio(1);
#pragma unroll
    for (int nt = 0; nt < 4; ++nt)
#pragma unroll
      for (int ks = 0; ks < 4; ++ks) {
        short8 kf = *(const short8*)&Kt[cur][nt * 16 + c16][((ks * 4 + quad) ^ c16) * 8];
#pragma unroll
        for (int mt = 0; mt < 2; ++mt)
          accS[mt][nt] = __builtin_amdgcn_mfma_f32_16x16x32_bf16(qf[mt][ks], kf, accS[mt][nt], 0, 0, 0);
      }
    __builtin_amdgcn_s_setprio(0);

    // ---- V frags to registers (reused by both strips) ----
    short8 vbreg[2][4];
#pragma unroll
    for (int ks2 = 0; ks2 < 2; ++ks2)
#pragma unroll
      for (int nt = 0; nt < 4; ++nt)
        vbreg[ks2][nt] =
            *(const short8*)&Vt[cur][nt * 16 + c16][(((ks2 * 4 + quad) ^ (c16 & 7)) & 7) * 8];

    // ---- per strip: softmax-lite + P roundtrip + PV ----
#pragma unroll
    for (int mt = 0; mt < 2; ++mt) {
      float s[4][4];
#pragma unroll
      for (int nt = 0; nt < 4; ++nt)
#pragma unroll
        for (int r = 0; r < 4; ++r) s[nt][r] = accS[mt][nt][r] * 0.125f;

      if (kt == 0 || (qt == 0 && wave == 0 && mt == 0)) {
#pragma unroll
        for (int nt = 0; nt < 4; ++nt)
#pragma unroll
          for (int r = 0; r < 4; ++r) {
            int kcol = kt * 64 + nt * 16 + c16;
            int qrow = qt * 128 + wave * 32 + mt * 16 + quad * 4 + r;
            float add = 0.f;
            if (qrow == 0 && kcol == 0) add = tcc;
            else if (qrow == 0) add = tco;
            else if (kcol == 0) add = toc;
            s[nt][r] += add * 0.125f;
          }
      }
#pragma unroll
      for (int nt = 0; nt < 4; ++nt)
#pragma unroll
        for (int r = 0; r < 4; ++r) {
          float p = __expf(s[nt][r]);
          lrow[mt][r] += p;
          int row = quad * 4 + r;
          int ch = nt * 2 + (c16 >> 3);
          Pt[wave][row][((ch ^ (row & 7)) * 8) + (c16 & 7)] = (short)f2bf(p);
        }
      __builtin_amdgcn_s_setprio(1);
#pragma unroll
      for (int ks2 = 0; ks2 < 2; ++ks2) {
        short8 pf = *(const short8*)&Pt[wave][c16][(((ks2 * 4 + quad) ^ (c16 & 7)) & 7) * 8];
#pragma unroll
        for (int nt = 0; nt < 4; ++nt)
          accO[mt][nt] = __builtin_amdgcn_mfma_f32_16x16x32_bf16(pf, vbreg[ks2][nt], accO[mt][nt], 0, 0, 0);
      }
      __builtin_amdgcn_s_setprio(0);
    }
    __syncthreads();  // drains next-tile DMA; protects buffer reuse
  }

  // one deferred l-reduction across the 16 c16 lanes
#pragma unroll
  for (int d = 1; d < 16; d <<= 1)
#pragma unroll
    for (int mt = 0; mt < 2; ++mt)
#pragma unroll
      for (int r = 0; r < 4; ++r) lrow[mt][r] += __shfl_xor(lrow[mt][r], d, 64);

#pragma unroll
  for (int mt = 0; mt < 2; ++mt)
#pragma unroll
    for (int nt = 0; nt < 4; ++nt)
#pragma unroll
      for (int r = 0; r < 4; ++r) {
        int qrow = qt * 128 + wave * 32 + mt * 16 + quad * 4 + r;
        O[((size_t)(b * SEQ + qrow)) * 1024 + h * 64 + nt * 16 + c16] =
            __float2bfloat16(accO[mt][nt][r] / lrow[mt][r]);
      }
#undef STAGE_K
#undef STAGE_V
}

extern "C" void kernel_launch(void* const* d_in, const int* in_sizes, int n_in,
                              void* d_out, int out_size, void* d_ws, size_t ws_size,
                              hipStream_t stream) {
  const void* q = d_in[0];
  const void* k = d_in[1];
  const void* v = d_in[2];
  const void* Wq = d_in[3];
  const void* bq = d_in[4];
  const void* Wk = d_in[5];
  const void* bk = d_in[6];
  const void* Wv = d_in[7];
  const void* bv = d_in[8];
  const void* Uq = d_in[9];
  const void* buq = d_in[10];
  const void* Uk = d_in[11];
  const void* buk = d_in[12];
  const void* pos = d_in[13];
  const void* th_cc = d_in[14];
  const void* th_co = d_in[15];
  const void* th_oc = d_in[16];
  const void* Wo = d_in[17];
  const void* bo = d_in[18];

  const int M = BS;  // 4096
  const size_t DD = (size_t)D_MODEL * D_MODEL;
  char* wsb = (char*)d_ws;
  int* flag = (int*)wsb;
  bf16* Qc = (bf16*)(wsb + 256);            // 8 MB
  bf16* Kc = Qc + (size_t)M * D_MODEL;      // 8 MB
  bf16* VcT = Kc + (size_t)M * D_MODEL;     // 8 MB, [D_MODEL][M]
  bf16* Qp = VcT + (size_t)M * D_MODEL;     // 2 MB
  bf16* Kp = Qp + (size_t)SEQ * D_MODEL;    // 2 MB
  u16* WT = (u16*)(Kp + (size_t)SEQ * D_MODEL);  // 6 x 2 MB
  bf16* AO = (bf16*)WT;  // aliases WqT..UqT (dead after g1); WoT (slot 5) untouched
  u16* Qb = WT + 6 * DD;                    // 8 MB bf16 copies of activations
  u16* Kb = Qb + (size_t)M * D_MODEL;       // 8 MB
  u16* Vb = Kb + (size_t)M * D_MODEL;       // 8 MB
  u16* Pb = Vb + (size_t)M * D_MODEL;       // 2 MB (first SEQ rows of pos_table)

  prep<<<dim3(1024, 1, 10), dim3(256), 0, stream>>>(q, k, v, pos, Wq, Wk, Wv, Uq, Uk, Wo,
                                                    Qb, Kb, Vb, Pb, WT, flag);

  GArgs g1 = {{Qb, Kb, Vb, Pb, Pb},
              {WT + 0 * DD, WT + 1 * DD, WT + 2 * DD, WT + 3 * DD, WT + 4 * DD},
              {bq, bk, bv, buq, buk},
              {Qc, Kc, VcT, Qp, Kp},
              {M, M, M, SEQ, SEQ},
              {1, 1, 2, 1, 1}};
  gemm_big<<<dim3(4, 16, 5), dim3(512), 0, stream>>>(g1, flag);

  flash_attn<<<dim3(NUM_HEADS, BATCH, SEQ / 128), dim3(256), 0, stream>>>(
      Qc, Kc, VcT, Qp, Kp, th_cc, th_co, th_oc, AO, flag);

  GArgs g2 = {{(const u16*)AO, (const u16*)AO, (const u16*)AO, (const u16*)AO, (const u16*)AO},
              {WT + 5 * DD, WT + 5 * DD, WT + 5 * DD, WT + 5 * DD, WT + 5 * DD},
              {bo, bo, bo, bo, bo},
              {d_out, d_out, d_out, d_out, d_out},
              {M, M, M, M, M},
              {0, 0, 0, 0, 0}};
  gemm_128<<<dim3(8, 32, 1), dim3(512), 0, stream>>>(g2, flag);
}

// Round 7
// 260.947 us; speedup vs baseline: 1.1043x; 1.0432x over previous
//
#include <hip/hip_runtime.h>
#include <hip/hip_bf16.h>

typedef __hip_bfloat16 bf16;
typedef unsigned short u16;
typedef __attribute__((ext_vector_type(8))) short short8;
typedef __attribute__((ext_vector_type(4))) short short4v;
typedef __attribute__((ext_vector_type(4))) float f32x4;

#define D_MODEL 1024
#define NUM_HEADS 16
#define DEPTH 64
#define BATCH 4
#define SEQ 1024
#define BS (BATCH * SEQ)

__device__ __forceinline__ float ldDyn(const void* p, size_t i, int isbf) {
  return isbf ? __bfloat162float(((const bf16*)p)[i]) : ((const float*)p)[i];
}
__device__ __forceinline__ u16 f2bf(float f) {
  bf16 h = __float2bfloat16(f);
  return *(u16*)&h;
}
// async global->LDS, 16B per lane; LDS dest = wave-uniform base + lane*16
__device__ __forceinline__ void gl2lds16(const void* g, void* l) {
  __builtin_amdgcn_global_load_lds((const __attribute__((address_space(1))) unsigned int*)g,
                                   (__attribute__((address_space(3))) unsigned int*)l, 16, 0, 0);
}

// Per-wave dtype detection via ballot: lane i checks q[2i] (same 64 values the
// old 64-iteration loop checked), ONE load per thread instead of 64. r6 PMC
// showed the old per-thread loop cost ~17us/CU of VMEM issue across 10240
// blocks (prep VALUBusy 28%, 1.6 TB/s on a streaming kernel).
__device__ __forceinline__ int detect_isbf(const u16* q) {
  const int lane = threadIdx.x & 63;
  u16 h = q[2 * lane];
  int e = (h >> 7) & 0xFF;
  unsigned long long m = __ballot(e >= 100 && e <= 150);
  return (__popcll(m) >= 48) ? 1 : 0;
}

// Merged prep kernel (detect + convert + weight transpose in one launch).
// z < 4: convert q/k/v/pos to bf16. z in [4,10): transpose weight z-4.
__global__ __launch_bounds__(256) void prep(
    const void* __restrict__ q, const void* __restrict__ k, const void* __restrict__ v,
    const void* __restrict__ pos, const void* __restrict__ W0, const void* __restrict__ W1,
    const void* __restrict__ W2, const void* __restrict__ W3, const void* __restrict__ W4,
    const void* __restrict__ W5, u16* __restrict__ Qb, u16* __restrict__ Kb,
    u16* __restrict__ Vb, u16* __restrict__ Pb, u16* __restrict__ WT,
    int* __restrict__ flag) {
  const int isbf = detect_isbf((const u16*)q);
  const int z = blockIdx.z;
  const int t = threadIdx.x;
  if (z == 0 && blockIdx.x == 0 && t == 0) *flag = isbf;

  if (z < 4) {
    const void* src = (z == 0) ? q : (z == 1) ? k : (z == 2) ? v : pos;
    u16* dst = (z == 0) ? Qb : (z == 1) ? Kb : (z == 2) ? Vb : Pb;
    const size_t n8 = ((z == 3) ? (size_t)SEQ * D_MODEL : (size_t)BS * D_MODEL) / 8;
    for (size_t i = (size_t)blockIdx.x * 256 + t; i < n8; i += (size_t)gridDim.x * 256) {
      short8 o;
      if (isbf) {
        o = ((const short8*)src)[i];
      } else {
        const float4* f = (const float4*)src + 2 * i;
        float4 lo = f[0], hi = f[1];
        u16* pv = (u16*)&o;
        pv[0] = f2bf(lo.x); pv[1] = f2bf(lo.y); pv[2] = f2bf(lo.z); pv[3] = f2bf(lo.w);
        pv[4] = f2bf(hi.x); pv[5] = f2bf(hi.y); pv[6] = f2bf(hi.z); pv[7] = f2bf(hi.w);
      }
      ((short8*)dst)[i] = o;
    }
  } else {
    const int w = z - 4;
    const void* W = (w == 0) ? W0 : (w == 1) ? W1 : (w == 2) ? W2
                   : (w == 3) ? W3 : (w == 4) ? W4 : W5;
    u16* out = WT + (size_t)w * D_MODEL * D_MODEL;
    __shared__ u16 tile[32][33];
    const int tx = t & 31, ty = t >> 5;
    const int r0 = (blockIdx.x >> 5) * 32, c0 = (blockIdx.x & 31) * 32;
#pragma unroll
    for (int i = 0; i < 4; ++i) {
      size_t gi = (size_t)(r0 + ty + 8 * i) * D_MODEL + c0 + tx;
      tile[ty + 8 * i][tx] = isbf ? ((const u16*)W)[gi] : f2bf(((const float*)W)[gi]);
    }
    __syncthreads();
    // vectorized writeback: one short4 (8B) store per thread (was 4 scalar 2B)
    const int orow = t >> 3, cg = t & 7;
    short4v pk;
#pragma unroll
    for (int j = 0; j < 4; ++j) pk[j] = (short)tile[cg * 4 + j][orow];
    *(short4v*)&out[(size_t)(c0 + orow) * 1024 + r0 + cg * 4] = pk;
  }
}

struct GArgs {
  const u16* A[5];
  const u16* W[5];
  const void* bias[5];
  void* C[5];
  int Mr[5];
  int om[5];
};

// ---------------- g1 kernel: 256x256 tile, 8 waves, split-step ----------------
// r5 measured 594 TF = the m233 2-phase ceiling (607). This version splits each
// BK=32 step into TWO barrier-separated sub-phases:
//   ph1: stage A-half(k+2) || ds_read bfv[4]+af[0..3] -> 16 MFMA
//   barrier
//   ph2: stage B-half(k+2) || ds_read af[4..7]        -> 16 MFMA
// (r6: neutral vs single-phase -- m196-consistent -- kept for the lower VGPR
// count and marginally better MfmaUtil.) Counted vmcnt(4) boundary; never
// drained to 0 inside the loop.
__global__ __launch_bounds__(512, 2) void gemm_big(GArgs ga, const int* __restrict__ flagp) {
  const int isbf = *flagp;
  const int z = blockIdx.z;
  const int M = ga.Mr[z];
  const int lin = blockIdx.x + 4 * blockIdx.y;  // 0..63
  const int xcd = lin & 7;
  const int idx = lin >> 3;                     // 0..7
  int rowb, colb;
  if (M >= 4096) {
    rowb = xcd * 2 + (idx & 1);                 // 0..15
    colb = idx >> 1;                            // 0..3
  } else {
    if (idx >= 2) return;
    rowb = idx * 2 + (xcd & 1);                 // 0..3
    colb = xcd >> 1;                            // 0..3
  }
  const int row0 = rowb * 256, col0 = colb * 256;
  if (row0 >= M) return;
  const u16* A = ga.A[z];
  const u16* WT = ga.W[z];
  const void* bias = ga.bias[z];
  void* C = ga.C[z];
  const int omode = ga.om[z];

  __shared__ short As[3][256][32];  // 48 KB
  __shared__ short Bs[3][256][32];  // 48 KB
  const int t = threadIdx.x;                    // 0..511
  const int wave = t >> 6, lane = t & 63;
  const int quad = lane >> 4, c16 = lane & 15;
  const int wrow = wave >> 2;                   // 0..1 : 128-row strip
  const int wcol = wave & 3;                    // 0..3 : 64-col strip

  f32x4 acc[8][4];
#pragma unroll
  for (int mt = 0; mt < 8; ++mt)
#pragma unroll
    for (int nt = 0; nt < 4; ++nt) acc[mt][nt] = {0.f, 0.f, 0.f, 0.f};

  // Global-side swizzle: LDS slot s of row r holds chunk s ^ f(r),
  // f(r) = (r + (r>>2)) & 3. 2 gloads per macro (A-only / B-only halves).
#define STAGE_A(K0, BUF)                                                                  \
  {                                                                                       \
    _Pragma("unroll") for (int j = 0; j < 2; ++j) {                                       \
      int L = t + 512 * j;                                                                \
      int r = L >> 2;                                                                     \
      int kc = (L & 3) ^ ((r + (r >> 2)) & 3);                                            \
      gl2lds16(A + (size_t)(row0 + r) * 1024 + (K0) + kc * 8,                             \
               (char*)&As[BUF][0][0] + (size_t)(j * 512 + wave * 64) * 16);               \
    }                                                                                     \
  }
#define STAGE_B(K0, BUF)                                                                  \
  {                                                                                       \
    _Pragma("unroll") for (int j = 0; j < 2; ++j) {                                       \
      int L = t + 512 * j;                                                                \
      int r = L >> 2;                                                                     \
      int kc = (L & 3) ^ ((r + (r >> 2)) & 3);                                            \
      gl2lds16(WT + (size_t)(col0 + r) * 1024 + (K0) + kc * 8,                            \
               (char*)&Bs[BUF][0][0] + (size_t)(j * 512 + wave * 64) * 16);               \
    }                                                                                     \
  }

  const int fsw = (c16 + (c16 >> 2)) & 3;  // = f(row) for row = base16k + c16

  // Prologue: stage tiles 0 and 1 fully.
  STAGE_A(0, 0);
  STAGE_B(0, 0);
  STAGE_A(32, 1);
  STAGE_B(32, 1);
#pragma unroll
  for (int kk = 0; kk < 31; ++kk) {
    const int cur = kk % 3;
    const int pre = (kk + 2) % 3;
    // boundary: stage kk landed (stage kk+1's 4 loads stay in flight)
    asm volatile("s_waitcnt vmcnt(4)\n\ts_barrier" ::: "memory");

    short8 bfv[4], afl[4], afh[4];
    // ---- sub-phase 1: stage A(k+2) || read bfv + af-low -> 16 MFMA ----
    if (kk < 30) STAGE_A((kk + 2) * 32, pre);
#pragma unroll
    for (int nt = 0; nt < 4; ++nt)
      bfv[nt] = *(const short8*)&Bs[cur][wcol * 64 + nt * 16 + c16][((quad ^ fsw) * 8)];
#pragma unroll
    for (int mt = 0; mt < 4; ++mt)
      afl[mt] = *(const short8*)&As[cur][wrow * 128 + mt * 16 + c16][((quad ^ fsw) * 8)];
    __builtin_amdgcn_s_setprio(1);
#pragma unroll
    for (int nt = 0; nt < 4; ++nt)
#pragma unroll
      for (int mt = 0; mt < 4; ++mt)
        acc[mt][nt] = __builtin_amdgcn_mfma_f32_16x16x32_bf16(afl[mt], bfv[nt], acc[mt][nt], 0, 0, 0);
    __builtin_amdgcn_s_setprio(0);

    asm volatile("s_barrier" ::: "memory");  // role-split boundary

    // ---- sub-phase 2: stage B(k+2) || read af-high -> 16 MFMA ----
    if (kk < 30) STAGE_B((kk + 2) * 32, pre);
#pragma unroll
    for (int mt = 0; mt < 4; ++mt)
      afh[mt] = *(const short8*)&As[cur][wrow * 128 + 64 + mt * 16 + c16][((quad ^ fsw) * 8)];
    __builtin_amdgcn_s_setprio(1);
#pragma unroll
    for (int nt = 0; nt < 4; ++nt)
#pragma unroll
      for (int mt = 0; mt < 4; ++mt)
        acc[mt + 4][nt] = __builtin_amdgcn_mfma_f32_16x16x32_bf16(afh[mt], bfv[nt], acc[mt + 4][nt], 0, 0, 0);
    __builtin_amdgcn_s_setprio(0);
  }
  // tail: step 31 (buf 1), everything resident
  asm volatile("s_waitcnt vmcnt(0)\n\ts_barrier" ::: "memory");
  {
    short8 bfv[4], af[8];
#pragma unroll
    for (int nt = 0; nt < 4; ++nt)
      bfv[nt] = *(const short8*)&Bs[1][wcol * 64 + nt * 16 + c16][((quad ^ fsw) * 8)];
#pragma unroll
    for (int mt = 0; mt < 8; ++mt)
      af[mt] = *(const short8*)&As[1][wrow * 128 + mt * 16 + c16][((quad ^ fsw) * 8)];
#pragma unroll
    for (int nt = 0; nt < 4; ++nt)
#pragma unroll
      for (int mt = 0; mt < 8; ++mt)
        acc[mt][nt] = __builtin_amdgcn_mfma_f32_16x16x32_bf16(af[mt], bfv[nt], acc[mt][nt], 0, 0, 0);
  }
#undef STAGE_A
#undef STAGE_B

#pragma unroll
  for (int nt = 0; nt < 4; ++nt) {
    int gc = col0 + wcol * 64 + nt * 16 + c16;
    float bb = ldDyn(bias, gc, isbf);
#pragma unroll
    for (int mt = 0; mt < 8; ++mt) {
      int gr0 = row0 + wrow * 128 + mt * 16 + quad * 4;
      if (omode == 2) {
        short4v pk;
#pragma unroll
        for (int r = 0; r < 4; ++r) pk[r] = (short)f2bf(acc[mt][nt][r] + bb);
        *(short4v*)&((u16*)C)[(size_t)gc * M + gr0] = pk;
      } else if (omode == 1 || isbf) {
#pragma unroll
        for (int r = 0; r < 4; ++r)
          ((bf16*)C)[(size_t)(gr0 + r) * 1024 + gc] = __float2bfloat16(acc[mt][nt][r] + bb);
      } else {
#pragma unroll
        for (int r = 0; r < 4; ++r)
          ((float*)C)[(size_t)(gr0 + r) * 1024 + gc] = acc[mt][nt][r] + bb;
      }
    }
  }
}

// ---------------- g2 kernel: 128x128 tile, 8 waves (round-4 structure) --------
// g2 is a single z-slice: 256 blocks, ~3 blocks/CU, 40 VGPR -- r4-proven.
__global__ __launch_bounds__(512) void gemm_128(GArgs ga, const int* __restrict__ flagp) {
  const int isbf = *flagp;
  const int z = blockIdx.z;
  const int M = ga.Mr[z];
  const int lin = blockIdx.x + 8 * blockIdx.y;  // 0..255
  const int xcd = lin & 7;
  const int loc = lin >> 3;                     // 0..31
  const int rowb = (loc & 3) * 8 + xcd;         // 0..31
  const int colb = loc >> 2;                    // 0..7
  const int row0 = rowb * 128, col0 = colb * 128;
  if (row0 >= M) return;
  const u16* A = ga.A[z];
  const u16* WT = ga.W[z];
  const void* bias = ga.bias[z];
  void* C = ga.C[z];
  const int omode = ga.om[z];

  __shared__ short As[3][128][32];  // 24 KB
  __shared__ short Bs[3][128][32];  // 24 KB
  const int t = threadIdx.x;                    // 0..511
  const int wave = t >> 6, lane = t & 63;
  const int quad = lane >> 4, c16 = lane & 15;
  const int wrow = wave >> 2;                   // 0..1 : 64-row strip
  const int wcol = wave & 3;                    // 0..3 : 32-col strip

  f32x4 acc[4][2];
#pragma unroll
  for (int mt = 0; mt < 4; ++mt)
#pragma unroll
    for (int nt = 0; nt < 2; ++nt) acc[mt][nt] = {0.f, 0.f, 0.f, 0.f};

#define G_STAGE(K0, BUF)                                                                  \
  {                                                                                       \
    int r = t >> 2;                                                                       \
    int kc = (t & 3) ^ ((r + (r >> 2)) & 3);                                              \
    gl2lds16(A + (size_t)(row0 + r) * 1024 + (K0) + kc * 8,                               \
             (char*)&As[BUF][0][0] + (size_t)(wave * 64) * 16);                           \
    gl2lds16(WT + (size_t)(col0 + r) * 1024 + (K0) + kc * 8,                              \
             (char*)&Bs[BUF][0][0] + (size_t)(wave * 64) * 16);                           \
  }

  const int fsw = (c16 + (c16 >> 2)) & 3;

#define COMPUTE(BUF)                                                                      \
  {                                                                                       \
    short8 af[4], bfv[2];                                                                 \
    _Pragma("unroll") for (int mt = 0; mt < 4; ++mt)                                      \
        af[mt] = *(const short8*)&As[BUF][wrow * 64 + mt * 16 + c16][((quad ^ fsw) * 8)]; \
    _Pragma("unroll") for (int nt = 0; nt < 2; ++nt)                                      \
        bfv[nt] = *(const short8*)&Bs[BUF][wcol * 32 + nt * 16 + c16][((quad ^ fsw) * 8)];\
    _Pragma("unroll") for (int nt = 0; nt < 2; ++nt)                                      \
      _Pragma("unroll") for (int mt = 0; mt < 4; ++mt)                                    \
          acc[mt][nt] =                                                                   \
              __builtin_amdgcn_mfma_f32_16x16x32_bf16(af[mt], bfv[nt], acc[mt][nt], 0, 0, 0); \
  }

  G_STAGE(0, 0);
  G_STAGE(32, 1);
#pragma unroll
  for (int kk = 0; kk < 31; ++kk) {
    asm volatile("s_waitcnt vmcnt(2)\n\ts_barrier" ::: "memory");
    if (kk < 30) G_STAGE((kk + 2) * 32, (kk + 2) % 3);
    COMPUTE(kk % 3);
  }
  asm volatile("s_waitcnt vmcnt(0)\n\ts_barrier" ::: "memory");
  COMPUTE(1);  // 31 % 3
#undef G_STAGE
#undef COMPUTE

#pragma unroll
  for (int nt = 0; nt < 2; ++nt) {
    int gc = col0 + wcol * 32 + nt * 16 + c16;
    float bb = ldDyn(bias, gc, isbf);
#pragma unroll
    for (int mt = 0; mt < 4; ++mt) {
      int gr0 = row0 + wrow * 64 + mt * 16 + quad * 4;
      if (omode == 2) {
        short4v pk;
#pragma unroll
        for (int r = 0; r < 4; ++r) pk[r] = (short)f2bf(acc[mt][nt][r] + bb);
        *(short4v*)&((u16*)C)[(size_t)gc * M + gr0] = pk;
      } else if (omode == 1 || isbf) {
#pragma unroll
        for (int r = 0; r < 4; ++r)
          ((bf16*)C)[(size_t)(gr0 + r) * 1024 + gc] = __float2bfloat16(acc[mt][nt][r] + bb);
      } else {
#pragma unroll
        for (int r = 0; r < 4; ++r)
          ((float*)C)[(size_t)(gr0 + r) * 1024 + gc] = acc[mt][nt][r] + bb;
      }
    }
  }
}

// Flash attention, m97-style: double-buffered async global_load_lds staging of
// the K-hat (64x128) and V^T (64x64) tiles; one barrier per kt drains the DMA
// (per-kt compute is long enough to cover the DMA latency). s_setprio around
// the MFMA clusters (m191: +4-7% on independent-block attention).
__global__ __launch_bounds__(256) void flash_attn(
    const bf16* __restrict__ Qc, const bf16* __restrict__ Kc, const bf16* __restrict__ VcT,
    const bf16* __restrict__ Qp, const bf16* __restrict__ Kp,
    const void* __restrict__ th_cc, const void* __restrict__ th_co,
    const void* __restrict__ th_oc, bf16* __restrict__ O, const int* __restrict__ flagp) {
  const int isbf = *flagp;
  const int h = blockIdx.x, b = blockIdx.y, qt = blockIdx.z;
  const int t = threadIdx.x, wave = t >> 6, lane = t & 63;
  const int quad = lane >> 4, c16 = lane & 15;

  __shared__ short Kt[2][64][128];  // [buf][key][aug dims], slot kc holds chunk kc^(key&15)
  __shared__ short Vt[2][64][64];   // [buf][d][keys], slot kc holds chunk kc^(d&7)
  __shared__ short Pt[4][16][64];   // per-wave P strip (mt-sequential), swizzled ^ (row&7)

  const float tcc = ldDyn(th_cc, h, isbf);
  const float tco = ldDyn(th_co, h, isbf);
  const float toc = ldDyn(th_oc, h, isbf);

  const bf16* kcb = Kc + (size_t)b * SEQ * 1024 + h * 64;
  const bf16* kpb = Kp + h * 64;
  const bf16* vtb = VcT + (size_t)(h * 64) * BS + (size_t)b * SEQ;

  // staging lane roles
  const int rwK = lane >> 4, kcK = lane & 15;  // K-hat: 4 rows/inst, 16 chunks/row
  const int rwV = lane >> 3, kcV = lane & 7;   // V^T : 8 rows/inst,  8 chunks/row

#define STAGE_K(KT2, BUF)                                                              \
  {                                                                                    \
    _Pragma("unroll") for (int i = 0; i < 4; ++i) {                                    \
      int r = wave * 16 + i * 4 + rwK;                                                 \
      int c = kcK ^ (r & 15);                                                          \
      int key = (KT2)*64 + r;                                                          \
      const bf16* src = (c < 8) ? kcb + (size_t)key * 1024 + c * 8                     \
                                : kpb + (size_t)key * 1024 + c * 8 - 64;               \
      gl2lds16(src, &Kt[BUF][wave * 16 + i * 4][0]);                                   \
    }                                                                                  \
  }
#define STAGE_V(KT2, BUF)                                                              \
  {                                                                                    \
    _Pragma("unroll") for (int j = 0; j < 2; ++j) {                                    \
      int d = wave * 16 + j * 8 + rwV;                                                 \
      int c = kcV ^ (d & 7);                                                           \
      gl2lds16(vtb + (size_t)d * BS + (KT2)*64 + c * 8, &Vt[BUF][wave * 16 + j * 8][0]); \
    }                                                                                  \
  }

  // Q A-frags (register-resident, 2 strips)
  short8 qf[2][4];
#pragma unroll
  for (int mt = 0; mt < 2; ++mt) {
    int qrow = qt * 128 + wave * 32 + mt * 16 + c16;
#pragma unroll
    for (int ks = 0; ks < 4; ++ks) {
      int d = ks * 32 + quad * 8;
      const bf16* src = (d < 64) ? Qc + ((size_t)(b * SEQ + qrow)) * 1024 + h * 64 + d
                                 : Qp + (size_t)qrow * 1024 + h * 64 + (d - 64);
      qf[mt][ks] = *(const short8*)src;
    }
    if (qrow == 0) {  // zero pos-half for q==0 (theta replaces pos there)
      qf[mt][2] = (short8)0;
      qf[mt][3] = (short8)0;
    }
  }

  f32x4 accO[2][4];
#pragma unroll
  for (int mt = 0; mt < 2; ++mt)
#pragma unroll
    for (int nt = 0; nt < 4; ++nt) accO[mt][nt] = {0.f, 0.f, 0.f, 0.f};
  float lrow[2][4] = {{0.f, 0.f, 0.f, 0.f}, {0.f, 0.f, 0.f, 0.f}};

  // prologue: stage tile 0, drain, zero key-0 pos-half (theta replaces it)
  STAGE_K(0, 0);
  STAGE_V(0, 0);
  __syncthreads();
  if (t < 8) *(short8*)&Kt[0][0][64 + t * 8] = (short8)0;  // row0 swizzle = identity
  __syncthreads();

  for (int kt = 0; kt < 16; ++kt) {
    const int cur = kt & 1, nxt = cur ^ 1;
    if (kt < 15) {
      STAGE_K(kt + 1, nxt);
      STAGE_V(kt + 1, nxt);
    }

    // ---- S = Q-hat (32x128) x K-hat^T from LDS ----
    f32x4 accS[2][4];
#pragma unroll
    for (int mt = 0; mt < 2; ++mt)
#pragma unroll
      for (int nt = 0; nt < 4; ++nt) accS[mt][nt] = {0.f, 0.f, 0.f, 0.f};
    __builtin_amdgcn_s_setprio(1);
#pragma unroll
    for (int nt = 0; nt < 4; ++nt)
#pragma unroll
      for (int ks = 0; ks < 4; ++ks) {
        short8 kf = *(const short8*)&Kt[cur][nt * 16 + c16][((ks * 4 + quad) ^ c16) * 8];
#pragma unroll
        for (int mt = 0; mt < 2; ++mt)
          accS[mt][nt] = __builtin_amdgcn_mfma_f32_16x16x32_bf16(qf[mt][ks], kf, accS[mt][nt], 0, 0, 0);
      }
    __builtin_amdgcn_s_setprio(0);

    // ---- V frags to registers (reused by both strips) ----
    short8 vbreg[2][4];
#pragma unroll
    for (int ks2 = 0; ks2 < 2; ++ks2)
#pragma unroll
      for (int nt = 0; nt < 4; ++nt)
        vbreg[ks2][nt] =
            *(const short8*)&Vt[cur][nt * 16 + c16][(((ks2 * 4 + quad) ^ (c16 & 7)) & 7) * 8];

    // ---- per strip: softmax-lite + P roundtrip + PV ----
#pragma unroll
    for (int mt = 0; mt < 2; ++mt) {
      float s[4][4];
#pragma unroll
      for (int nt = 0; nt < 4; ++nt)
#pragma unroll
        for (int r = 0; r < 4; ++r) s[nt][r] = accS[mt][nt][r] * 0.125f;

      if (kt == 0 || (qt == 0 && wave == 0 && mt == 0)) {
#pragma unroll
        for (int nt = 0; nt < 4; ++nt)
#pragma unroll
          for (int r = 0; r < 4; ++r) {
            int kcol = kt * 64 + nt * 16 + c16;
            int qrow = qt * 128 + wave * 32 + mt * 16 + quad * 4 + r;
            float add = 0.f;
            if (qrow == 0 && kcol == 0) add = tcc;
            else if (qrow == 0) add = tco;
            else if (kcol == 0) add = toc;
            s[nt][r] += add * 0.125f;
          }
      }
#pragma unroll
      for (int nt = 0; nt < 4; ++nt)
#pragma unroll
        for (int r = 0; r < 4; ++r) {
          float p = __expf(s[nt][r]);
          lrow[mt][r] += p;
          int row = quad * 4 + r;
          int ch = nt * 2 + (c16 >> 3);
          Pt[wave][row][((ch ^ (row & 7)) * 8) + (c16 & 7)] = (short)f2bf(p);
        }
      __builtin_amdgcn_s_setprio(1);
#pragma unroll
      for (int ks2 = 0; ks2 < 2; ++ks2) {
        short8 pf = *(const short8*)&Pt[wave][c16][(((ks2 * 4 + quad) ^ (c16 & 7)) & 7) * 8];
#pragma unroll
        for (int nt = 0; nt < 4; ++nt)
          accO[mt][nt] = __builtin_amdgcn_mfma_f32_16x16x32_bf16(pf, vbreg[ks2][nt], accO[mt][nt], 0, 0, 0);
      }
      __builtin_amdgcn_s_setprio(0);
    }
    __syncthreads();  // drains next-tile DMA; protects buffer reuse
  }

  // one deferred l-reduction across the 16 c16 lanes
#pragma unroll
  for (int d = 1; d < 16; d <<= 1)
#pragma unroll
    for (int mt = 0; mt < 2; ++mt)
#pragma unroll
      for (int r = 0; r < 4; ++r) lrow[mt][r] += __shfl_xor(lrow[mt][r], d, 64);

#pragma unroll
  for (int mt = 0; mt < 2; ++mt)
#pragma unroll
    for (int nt = 0; nt < 4; ++nt)
#pragma unroll
      for (int r = 0; r < 4; ++r) {
        int qrow = qt * 128 + wave * 32 + mt * 16 + quad * 4 + r;
        O[((size_t)(b * SEQ + qrow)) * 1024 + h * 64 + nt * 16 + c16] =
            __float2bfloat16(accO[mt][nt][r] / lrow[mt][r]);
      }
#undef STAGE_K
#undef STAGE_V
}

extern "C" void kernel_launch(void* const* d_in, const int* in_sizes, int n_in,
                              void* d_out, int out_size, void* d_ws, size_t ws_size,
                              hipStream_t stream) {
  const void* q = d_in[0];
  const void* k = d_in[1];
  const void* v = d_in[2];
  const void* Wq = d_in[3];
  const void* bq = d_in[4];
  const void* Wk = d_in[5];
  const void* bk = d_in[6];
  const void* Wv = d_in[7];
  const void* bv = d_in[8];
  const void* Uq = d_in[9];
  const void* buq = d_in[10];
  const void* Uk = d_in[11];
  const void* buk = d_in[12];
  const void* pos = d_in[13];
  const void* th_cc = d_in[14];
  const void* th_co = d_in[15];
  const void* th_oc = d_in[16];
  const void* Wo = d_in[17];
  const void* bo = d_in[18];

  const int M = BS;  // 4096
  const size_t DD = (size_t)D_MODEL * D_MODEL;
  char* wsb = (char*)d_ws;
  int* flag = (int*)wsb;
  bf16* Qc = (bf16*)(wsb + 256);            // 8 MB
  bf16* Kc = Qc + (size_t)M * D_MODEL;      // 8 MB
  bf16* VcT = Kc + (size_t)M * D_MODEL;     // 8 MB, [D_MODEL][M]
  bf16* Qp = VcT + (size_t)M * D_MODEL;     // 2 MB
  bf16* Kp = Qp + (size_t)SEQ * D_MODEL;    // 2 MB
  u16* WT = (u16*)(Kp + (size_t)SEQ * D_MODEL);  // 6 x 2 MB
  bf16* AO = (bf16*)WT;  // aliases WqT..UqT (dead after g1); WoT (slot 5) untouched
  u16* Qb = WT + 6 * DD;                    // 8 MB bf16 copies of activations
  u16* Kb = Qb + (size_t)M * D_MODEL;       // 8 MB
  u16* Vb = Kb + (size_t)M * D_MODEL;       // 8 MB
  u16* Pb = Vb + (size_t)M * D_MODEL;       // 2 MB (first SEQ rows of pos_table)

  prep<<<dim3(1024, 1, 10), dim3(256), 0, stream>>>(q, k, v, pos, Wq, Wk, Wv, Uq, Uk, Wo,
                                                    Qb, Kb, Vb, Pb, WT, flag);

  GArgs g1 = {{Qb, Kb, Vb, Pb, Pb},
              {WT + 0 * DD, WT + 1 * DD, WT + 2 * DD, WT + 3 * DD, WT + 4 * DD},
              {bq, bk, bv, buq, buk},
              {Qc, Kc, VcT, Qp, Kp},
              {M, M, M, SEQ, SEQ},
              {1, 1, 2, 1, 1}};
  gemm_big<<<dim3(4, 16, 5), dim3(512), 0, stream>>>(g1, flag);

  flash_attn<<<dim3(NUM_HEADS, BATCH, SEQ / 128), dim3(256), 0, stream>>>(
      Qc, Kc, VcT, Qp, Kp, th_cc, th_co, th_oc, AO, flag);

  GArgs g2 = {{(const u16*)AO, (const u16*)AO, (const u16*)AO, (const u16*)AO, (const u16*)AO},
              {WT + 5 * DD, WT + 5 * DD, WT + 5 * DD, WT + 5 * DD, WT + 5 * DD},
              {bo, bo, bo, bo, bo},
              {d_out, d_out, d_out, d_out, d_out},
              {M, M, M, M, M},
              {0, 0, 0, 0, 0}};
  gemm_128<<<dim3(8, 32, 1), dim3(512), 0, stream>>>(g2, flag);
}

// Round 9
// 260.336 us; speedup vs baseline: 1.1069x; 1.0023x over previous
//
#include <hip/hip_runtime.h>
#include <hip/hip_bf16.h>

typedef __hip_bfloat16 bf16;
typedef unsigned short u16;
typedef __attribute__((ext_vector_type(8))) short short8;
typedef __attribute__((ext_vector_type(4))) short short4v;
typedef __attribute__((ext_vector_type(4))) float f32x4;

#define D_MODEL 1024
#define NUM_HEADS 16
#define DEPTH 64
#define BATCH 4
#define SEQ 1024
#define BS (BATCH * SEQ)

__device__ __forceinline__ float ldDyn(const void* p, size_t i, int isbf) {
  return isbf ? __bfloat162float(((const bf16*)p)[i]) : ((const float*)p)[i];
}
__device__ __forceinline__ u16 f2bf(float f) {
  bf16 h = __float2bfloat16(f);
  return *(u16*)&h;
}
// async global->LDS, 16B per lane; LDS dest = wave-uniform base + lane*16
__device__ __forceinline__ void gl2lds16(const void* g, void* l) {
  __builtin_amdgcn_global_load_lds((const __attribute__((address_space(1))) unsigned int*)g,
                                   (__attribute__((address_space(3))) unsigned int*)l, 16, 0, 0);
}

// Per-wave dtype detection via ballot: lane i checks q[2i]; one load/thread.
__device__ __forceinline__ int detect_isbf(const u16* q) {
  const int lane = threadIdx.x & 63;
  u16 h = q[2 * lane];
  int e = (h >> 7) & 0xFF;
  unsigned long long m = __ballot(e >= 100 && e <= 150);
  return (__popcll(m) >= 48) ? 1 : 0;
}

// Merged prep kernel (detect + convert + weight transpose in one launch).
// z < 4: convert q/k/v/pos to bf16. z in [4,10): transpose weight z-4.
__global__ __launch_bounds__(256) void prep(
    const void* __restrict__ q, const void* __restrict__ k, const void* __restrict__ v,
    const void* __restrict__ pos, const void* __restrict__ W0, const void* __restrict__ W1,
    const void* __restrict__ W2, const void* __restrict__ W3, const void* __restrict__ W4,
    const void* __restrict__ W5, u16* __restrict__ Qb, u16* __restrict__ Kb,
    u16* __restrict__ Vb, u16* __restrict__ Pb, u16* __restrict__ WT,
    int* __restrict__ flag) {
  const int isbf = detect_isbf((const u16*)q);
  const int z = blockIdx.z;
  const int t = threadIdx.x;
  if (z == 0 && blockIdx.x == 0 && t == 0) *flag = isbf;

  if (z < 4) {
    const void* src = (z == 0) ? q : (z == 1) ? k : (z == 2) ? v : pos;
    u16* dst = (z == 0) ? Qb : (z == 1) ? Kb : (z == 2) ? Vb : Pb;
    const size_t n8 = ((z == 3) ? (size_t)SEQ * D_MODEL : (size_t)BS * D_MODEL) / 8;
    for (size_t i = (size_t)blockIdx.x * 256 + t; i < n8; i += (size_t)gridDim.x * 256) {
      short8 o;
      if (isbf) {
        o = ((const short8*)src)[i];
      } else {
        const float4* f = (const float4*)src + 2 * i;
        float4 lo = f[0], hi = f[1];
        u16* pv = (u16*)&o;
        pv[0] = f2bf(lo.x); pv[1] = f2bf(lo.y); pv[2] = f2bf(lo.z); pv[3] = f2bf(lo.w);
        pv[4] = f2bf(hi.x); pv[5] = f2bf(hi.y); pv[6] = f2bf(hi.z); pv[7] = f2bf(hi.w);
      }
      ((short8*)dst)[i] = o;
    }
  } else {
    const int w = z - 4;
    const void* W = (w == 0) ? W0 : (w == 1) ? W1 : (w == 2) ? W2
                   : (w == 3) ? W3 : (w == 4) ? W4 : W5;
    u16* out = WT + (size_t)w * D_MODEL * D_MODEL;
    __shared__ u16 tile[32][33];
    const int tx = t & 31, ty = t >> 5;
    const int r0 = (blockIdx.x >> 5) * 32, c0 = (blockIdx.x & 31) * 32;
#pragma unroll
    for (int i = 0; i < 4; ++i) {
      size_t gi = (size_t)(r0 + ty + 8 * i) * D_MODEL + c0 + tx;
      tile[ty + 8 * i][tx] = isbf ? ((const u16*)W)[gi] : f2bf(((const float*)W)[gi]);
    }
    __syncthreads();
    // vectorized writeback: one short4 (8B) store per thread
    const int orow = t >> 3, cg = t & 7;
    short4v pk;
#pragma unroll
    for (int j = 0; j < 4; ++j) pk[j] = (short)tile[cg * 4 + j][orow];
    *(short4v*)&out[(size_t)(c0 + orow) * 1024 + r0 + cg * 4] = pk;
  }
}

struct GArgs {
  const u16* A[5];
  const u16* W[5];
  const void* bias[5];
  void* C[5];
  int Mr[5];
  int om[5];
};

// ---------------- g1 kernel: 256x256 tile, 8 waves, split-step ----------------
// At the m233 2-phase structural ceiling (~607 TF). Counted vmcnt(4) boundary;
// never drained to 0 inside the loop.
__global__ __launch_bounds__(512, 2) void gemm_big(GArgs ga, const int* __restrict__ flagp) {
  const int isbf = *flagp;
  const int z = blockIdx.z;
  const int M = ga.Mr[z];
  const int lin = blockIdx.x + 4 * blockIdx.y;  // 0..63
  const int xcd = lin & 7;
  const int idx = lin >> 3;                     // 0..7
  int rowb, colb;
  if (M >= 4096) {
    rowb = xcd * 2 + (idx & 1);                 // 0..15
    colb = idx >> 1;                            // 0..3
  } else {
    if (idx >= 2) return;
    rowb = idx * 2 + (xcd & 1);                 // 0..3
    colb = xcd >> 1;                            // 0..3
  }
  const int row0 = rowb * 256, col0 = colb * 256;
  if (row0 >= M) return;
  const u16* A = ga.A[z];
  const u16* WT = ga.W[z];
  const void* bias = ga.bias[z];
  void* C = ga.C[z];
  const int omode = ga.om[z];

  __shared__ short As[3][256][32];  // 48 KB
  __shared__ short Bs[3][256][32];  // 48 KB
  const int t = threadIdx.x;                    // 0..511
  const int wave = t >> 6, lane = t & 63;
  const int quad = lane >> 4, c16 = lane & 15;
  const int wrow = wave >> 2;                   // 0..1 : 128-row strip
  const int wcol = wave & 3;                    // 0..3 : 64-col strip

  f32x4 acc[8][4];
#pragma unroll
  for (int mt = 0; mt < 8; ++mt)
#pragma unroll
    for (int nt = 0; nt < 4; ++nt) acc[mt][nt] = {0.f, 0.f, 0.f, 0.f};

#define STAGE_A(K0, BUF)                                                                  \
  {                                                                                       \
    _Pragma("unroll") for (int j = 0; j < 2; ++j) {                                       \
      int L = t + 512 * j;                                                                \
      int r = L >> 2;                                                                     \
      int kc = (L & 3) ^ ((r + (r >> 2)) & 3);                                            \
      gl2lds16(A + (size_t)(row0 + r) * 1024 + (K0) + kc * 8,                             \
               (char*)&As[BUF][0][0] + (size_t)(j * 512 + wave * 64) * 16);               \
    }                                                                                     \
  }
#define STAGE_B(K0, BUF)                                                                  \
  {                                                                                       \
    _Pragma("unroll") for (int j = 0; j < 2; ++j) {                                       \
      int L = t + 512 * j;                                                                \
      int r = L >> 2;                                                                     \
      int kc = (L & 3) ^ ((r + (r >> 2)) & 3);                                            \
      gl2lds16(WT + (size_t)(col0 + r) * 1024 + (K0) + kc * 8,                            \
               (char*)&Bs[BUF][0][0] + (size_t)(j * 512 + wave * 64) * 16);               \
    }                                                                                     \
  }

  const int fsw = (c16 + (c16 >> 2)) & 3;  // = f(row) for row = base16k + c16

  STAGE_A(0, 0);
  STAGE_B(0, 0);
  STAGE_A(32, 1);
  STAGE_B(32, 1);
#pragma unroll
  for (int kk = 0; kk < 31; ++kk) {
    const int cur = kk % 3;
    const int pre = (kk + 2) % 3;
    asm volatile("s_waitcnt vmcnt(4)\n\ts_barrier" ::: "memory");

    short8 bfv[4], afl[4], afh[4];
    // ---- sub-phase 1: stage A(k+2) || read bfv + af-low -> 16 MFMA ----
    if (kk < 30) STAGE_A((kk + 2) * 32, pre);
#pragma unroll
    for (int nt = 0; nt < 4; ++nt)
      bfv[nt] = *(const short8*)&Bs[cur][wcol * 64 + nt * 16 + c16][((quad ^ fsw) * 8)];
#pragma unroll
    for (int mt = 0; mt < 4; ++mt)
      afl[mt] = *(const short8*)&As[cur][wrow * 128 + mt * 16 + c16][((quad ^ fsw) * 8)];
    __builtin_amdgcn_s_setprio(1);
#pragma unroll
    for (int nt = 0; nt < 4; ++nt)
#pragma unroll
      for (int mt = 0; mt < 4; ++mt)
        acc[mt][nt] = __builtin_amdgcn_mfma_f32_16x16x32_bf16(afl[mt], bfv[nt], acc[mt][nt], 0, 0, 0);
    __builtin_amdgcn_s_setprio(0);

    asm volatile("s_barrier" ::: "memory");  // role-split boundary

    // ---- sub-phase 2: stage B(k+2) || read af-high -> 16 MFMA ----
    if (kk < 30) STAGE_B((kk + 2) * 32, pre);
#pragma unroll
    for (int mt = 0; mt < 4; ++mt)
      afh[mt] = *(const short8*)&As[cur][wrow * 128 + 64 + mt * 16 + c16][((quad ^ fsw) * 8)];
    __builtin_amdgcn_s_setprio(1);
#pragma unroll
    for (int nt = 0; nt < 4; ++nt)
#pragma unroll
      for (int mt = 0; mt < 4; ++mt)
        acc[mt + 4][nt] = __builtin_amdgcn_mfma_f32_16x16x32_bf16(afh[mt], bfv[nt], acc[mt + 4][nt], 0, 0, 0);
    __builtin_amdgcn_s_setprio(0);
  }
  asm volatile("s_waitcnt vmcnt(0)\n\ts_barrier" ::: "memory");
  {
    short8 bfv[4], af[8];
#pragma unroll
    for (int nt = 0; nt < 4; ++nt)
      bfv[nt] = *(const short8*)&Bs[1][wcol * 64 + nt * 16 + c16][((quad ^ fsw) * 8)];
#pragma unroll
    for (int mt = 0; mt < 8; ++mt)
      af[mt] = *(const short8*)&As[1][wrow * 128 + mt * 16 + c16][((quad ^ fsw) * 8)];
#pragma unroll
    for (int nt = 0; nt < 4; ++nt)
#pragma unroll
      for (int mt = 0; mt < 8; ++mt)
        acc[mt][nt] = __builtin_amdgcn_mfma_f32_16x16x32_bf16(af[mt], bfv[nt], acc[mt][nt], 0, 0, 0);
  }
#undef STAGE_A
#undef STAGE_B

#pragma unroll
  for (int nt = 0; nt < 4; ++nt) {
    int gc = col0 + wcol * 64 + nt * 16 + c16;
    float bb = ldDyn(bias, gc, isbf);
#pragma unroll
    for (int mt = 0; mt < 8; ++mt) {
      int gr0 = row0 + wrow * 128 + mt * 16 + quad * 4;
      if (omode == 2) {
        short4v pk;
#pragma unroll
        for (int r = 0; r < 4; ++r) pk[r] = (short)f2bf(acc[mt][nt][r] + bb);
        *(short4v*)&((u16*)C)[(size_t)gc * M + gr0] = pk;
      } else if (omode == 1 || isbf) {
#pragma unroll
        for (int r = 0; r < 4; ++r)
          ((bf16*)C)[(size_t)(gr0 + r) * 1024 + gc] = __float2bfloat16(acc[mt][nt][r] + bb);
      } else {
#pragma unroll
        for (int r = 0; r < 4; ++r)
          ((float*)C)[(size_t)(gr0 + r) * 1024 + gc] = acc[mt][nt][r] + bb;
      }
    }
  }
}

// ---------------- g2 kernel: 128x128 tile, 8 waves (round-4 structure) --------
__global__ __launch_bounds__(512) void gemm_128(GArgs ga, const int* __restrict__ flagp) {
  const int isbf = *flagp;
  const int z = blockIdx.z;
  const int M = ga.Mr[z];
  const int lin = blockIdx.x + 8 * blockIdx.y;  // 0..255
  const int xcd = lin & 7;
  const int loc = lin >> 3;                     // 0..31
  const int rowb = (loc & 3) * 8 + xcd;         // 0..31
  const int colb = loc >> 2;                    // 0..7
  const int row0 = rowb * 128, col0 = colb * 128;
  if (row0 >= M) return;
  const u16* A = ga.A[z];
  const u16* WT = ga.W[z];
  const void* bias = ga.bias[z];
  void* C = ga.C[z];
  const int omode = ga.om[z];

  __shared__ short As[3][128][32];  // 24 KB
  __shared__ short Bs[3][128][32];  // 24 KB
  const int t = threadIdx.x;                    // 0..511
  const int wave = t >> 6, lane = t & 63;
  const int quad = lane >> 4, c16 = lane & 15;
  const int wrow = wave >> 2;                   // 0..1 : 64-row strip
  const int wcol = wave & 3;                    // 0..3 : 32-col strip

  f32x4 acc[4][2];
#pragma unroll
  for (int mt = 0; mt < 4; ++mt)
#pragma unroll
    for (int nt = 0; nt < 2; ++nt) acc[mt][nt] = {0.f, 0.f, 0.f, 0.f};

#define G_STAGE(K0, BUF)                                                                  \
  {                                                                                       \
    int r = t >> 2;                                                                       \
    int kc = (t & 3) ^ ((r + (r >> 2)) & 3);                                              \
    gl2lds16(A + (size_t)(row0 + r) * 1024 + (K0) + kc * 8,                               \
             (char*)&As[BUF][0][0] + (size_t)(wave * 64) * 16);                           \
    gl2lds16(WT + (size_t)(col0 + r) * 1024 + (K0) + kc * 8,                              \
             (char*)&Bs[BUF][0][0] + (size_t)(wave * 64) * 16);                           \
  }

  const int fsw = (c16 + (c16 >> 2)) & 3;

#define COMPUTE(BUF)                                                                      \
  {                                                                                       \
    short8 af[4], bfv[2];                                                                 \
    _Pragma("unroll") for (int mt = 0; mt < 4; ++mt)                                      \
        af[mt] = *(const short8*)&As[BUF][wrow * 64 + mt * 16 + c16][((quad ^ fsw) * 8)]; \
    _Pragma("unroll") for (int nt = 0; nt < 2; ++nt)                                      \
        bfv[nt] = *(const short8*)&Bs[BUF][wcol * 32 + nt * 16 + c16][((quad ^ fsw) * 8)];\
    _Pragma("unroll") for (int nt = 0; nt < 2; ++nt)                                      \
      _Pragma("unroll") for (int mt = 0; mt < 4; ++mt)                                    \
          acc[mt][nt] =                                                                   \
              __builtin_amdgcn_mfma_f32_16x16x32_bf16(af[mt], bfv[nt], acc[mt][nt], 0, 0, 0); \
  }

  G_STAGE(0, 0);
  G_STAGE(32, 1);
#pragma unroll
  for (int kk = 0; kk < 31; ++kk) {
    asm volatile("s_waitcnt vmcnt(2)\n\ts_barrier" ::: "memory");
    if (kk < 30) G_STAGE((kk + 2) * 32, (kk + 2) % 3);
    COMPUTE(kk % 3);
  }
  asm volatile("s_waitcnt vmcnt(0)\n\ts_barrier" ::: "memory");
  COMPUTE(1);  // 31 % 3
#undef G_STAGE
#undef COMPUTE

#pragma unroll
  for (int nt = 0; nt < 2; ++nt) {
    int gc = col0 + wcol * 32 + nt * 16 + c16;
    float bb = ldDyn(bias, gc, isbf);
#pragma unroll
    for (int mt = 0; mt < 4; ++mt) {
      int gr0 = row0 + wrow * 64 + mt * 16 + quad * 4;
      if (omode == 2) {
        short4v pk;
#pragma unroll
        for (int r = 0; r < 4; ++r) pk[r] = (short)f2bf(acc[mt][nt][r] + bb);
        *(short4v*)&((u16*)C)[(size_t)gc * M + gr0] = pk;
      } else if (omode == 1 || isbf) {
#pragma unroll
        for (int r = 0; r < 4; ++r)
          ((bf16*)C)[(size_t)(gr0 + r) * 1024 + gc] = __float2bfloat16(acc[mt][nt][r] + bb);
      } else {
#pragma unroll
        for (int r = 0; r < 4; ++r)
          ((float*)C)[(size_t)(gr0 + r) * 1024 + gc] = acc[mt][nt][r] + bb;
      }
    }
  }
}

// Flash attention, round-9: REVERT to the proven round-7 4-wave kernel, plus
// ONE surgical change: single-buffer V. V-frags are copied to registers
// (vbreg) right after QK^T, so the V LDS tile is dead from that point.
// Vt [2][64][64] -> [64][64] (-8 KB => LDS 48 KB => 3 blocks/CU, was 2).
// STAGE_V(kt+1) moves to after the vbreg loads, behind a raw
// s_waitcnt lgkmcnt(0)+s_barrier (orders all waves' V reads before the
// overwrite WITHOUT draining the in-flight K DMA). End-of-loop __syncthreads
// drains both DMAs as before. All indexing byte-identical to round-7.
__global__ __launch_bounds__(256) void flash_attn(
    const bf16* __restrict__ Qc, const bf16* __restrict__ Kc, const bf16* __restrict__ VcT,
    const bf16* __restrict__ Qp, const bf16* __restrict__ Kp,
    const void* __restrict__ th_cc, const void* __restrict__ th_co,
    const void* __restrict__ th_oc, bf16* __restrict__ O, const int* __restrict__ flagp) {
  const int isbf = *flagp;
  const int h = blockIdx.x, b = blockIdx.y, qt = blockIdx.z;
  const int t = threadIdx.x, wave = t >> 6, lane = t & 63;
  const int quad = lane >> 4, c16 = lane & 15;

  __shared__ short Kt[2][64][128];  // 32 KB, slot kc holds chunk kc^(key&15)
  __shared__ short Vt[64][64];      // 8 KB single-buffer, slot kc holds chunk kc^(d&7)
  __shared__ short Pt[4][16][64];   // 8 KB per-wave P strip, swizzled ^ (row&7)

  const float tcc = ldDyn(th_cc, h, isbf);
  const float tco = ldDyn(th_co, h, isbf);
  const float toc = ldDyn(th_oc, h, isbf);

  const bf16* kcb = Kc + (size_t)b * SEQ * 1024 + h * 64;
  const bf16* kpb = Kp + h * 64;
  const bf16* vtb = VcT + (size_t)(h * 64) * BS + (size_t)b * SEQ;

  // staging lane roles
  const int rwK = lane >> 4, kcK = lane & 15;  // K-hat: 4 rows/inst, 16 chunks/row
  const int rwV = lane >> 3, kcV = lane & 7;   // V^T : 8 rows/inst,  8 chunks/row

#define STAGE_K(KT2, BUF)                                                              \
  {                                                                                    \
    _Pragma("unroll") for (int i = 0; i < 4; ++i) {                                    \
      int r = wave * 16 + i * 4 + rwK;                                                 \
      int c = kcK ^ (r & 15);                                                          \
      int key = (KT2)*64 + r;                                                          \
      const bf16* src = (c < 8) ? kcb + (size_t)key * 1024 + c * 8                     \
                                : kpb + (size_t)key * 1024 + c * 8 - 64;               \
      gl2lds16(src, &Kt[BUF][wave * 16 + i * 4][0]);                                   \
    }                                                                                  \
  }
#define STAGE_V(KT2)                                                                   \
  {                                                                                    \
    _Pragma("unroll") for (int j = 0; j < 2; ++j) {                                    \
      int d = wave * 16 + j * 8 + rwV;                                                 \
      int c = kcV ^ (d & 7);                                                           \
      gl2lds16(vtb + (size_t)d * BS + (KT2)*64 + c * 8, &Vt[wave * 16 + j * 8][0]);    \
    }                                                                                  \
  }

  // Q A-frags (register-resident, 2 strips)
  short8 qf[2][4];
#pragma unroll
  for (int mt = 0; mt < 2; ++mt) {
    int qrow = qt * 128 + wave * 32 + mt * 16 + c16;
#pragma unroll
    for (int ks = 0; ks < 4; ++ks) {
      int d = ks * 32 + quad * 8;
      const bf16* src = (d < 64) ? Qc + ((size_t)(b * SEQ + qrow)) * 1024 + h * 64 + d
                                 : Qp + (size_t)qrow * 1024 + h * 64 + (d - 64);
      qf[mt][ks] = *(const short8*)src;
    }
    if (qrow == 0) {  // zero pos-half for q==0 (theta replaces pos there)
      qf[mt][2] = (short8)0;
      qf[mt][3] = (short8)0;
    }
  }

  f32x4 accO[2][4];
#pragma unroll
  for (int mt = 0; mt < 2; ++mt)
#pragma unroll
    for (int nt = 0; nt < 4; ++nt) accO[mt][nt] = {0.f, 0.f, 0.f, 0.f};
  float lrow[2][4] = {{0.f, 0.f, 0.f, 0.f}, {0.f, 0.f, 0.f, 0.f}};

  // prologue: stage tile 0, drain, zero key-0 pos-half (theta replaces it)
  STAGE_K(0, 0);
  STAGE_V(0);
  __syncthreads();
  if (t < 8) *(short8*)&Kt[0][0][64 + t * 8] = (short8)0;  // row0 swizzle = identity
  __syncthreads();

  for (int kt = 0; kt < 16; ++kt) {
    const int cur = kt & 1, nxt = cur ^ 1;
    if (kt < 15) STAGE_K(kt + 1, nxt);

    // ---- S = Q-hat (32x128) x K-hat^T from LDS ----
    f32x4 accS[2][4];
#pragma unroll
    for (int mt = 0; mt < 2; ++mt)
#pragma unroll
      for (int nt = 0; nt < 4; ++nt) accS[mt][nt] = {0.f, 0.f, 0.f, 0.f};
    __builtin_amdgcn_s_setprio(1);
#pragma unroll
    for (int nt = 0; nt < 4; ++nt)
#pragma unroll
      for (int ks = 0; ks < 4; ++ks) {
        short8 kf = *(const short8*)&Kt[cur][nt * 16 + c16][((ks * 4 + quad) ^ c16) * 8];
#pragma unroll
        for (int mt = 0; mt < 2; ++mt)
          accS[mt][nt] = __builtin_amdgcn_mfma_f32_16x16x32_bf16(qf[mt][ks], kf, accS[mt][nt], 0, 0, 0);
      }
    __builtin_amdgcn_s_setprio(0);

    // ---- V frags to registers (reused by both strips) ----
    short8 vbreg[2][4];
#pragma unroll
    for (int ks2 = 0; ks2 < 2; ++ks2)
#pragma unroll
      for (int nt = 0; nt < 4; ++nt)
        vbreg[ks2][nt] =
            *(const short8*)&Vt[nt * 16 + c16][(((ks2 * 4 + quad) ^ (c16 & 7)) & 7) * 8];

    // all waves have V(kt) in registers; then overwrite Vt with V(kt+1).
    // raw lgkmcnt-only wait: the in-flight K DMA (vmcnt) is NOT drained.
    asm volatile("s_waitcnt lgkmcnt(0)\n\ts_barrier" ::: "memory");
    if (kt < 15) STAGE_V(kt + 1);

    // ---- per strip: softmax-lite + P roundtrip + PV ----
#pragma unroll
    for (int mt = 0; mt < 2; ++mt) {
      float s[4][4];
#pragma unroll
      for (int nt = 0; nt < 4; ++nt)
#pragma unroll
        for (int r = 0; r < 4; ++r) s[nt][r] = accS[mt][nt][r] * 0.125f;

      if (kt == 0 || (qt == 0 && wave == 0 && mt == 0)) {
#pragma unroll
        for (int nt = 0; nt < 4; ++nt)
#pragma unroll
          for (int r = 0; r < 4; ++r) {
            int kcol = kt * 64 + nt * 16 + c16;
            int qrow = qt * 128 + wave * 32 + mt * 16 + quad * 4 + r;
            float add = 0.f;
            if (qrow == 0 && kcol == 0) add = tcc;
            else if (qrow == 0) add = tco;
            else if (kcol == 0) add = toc;
            s[nt][r] += add * 0.125f;
          }
      }
#pragma unroll
      for (int nt = 0; nt < 4; ++nt)
#pragma unroll
        for (int r = 0; r < 4; ++r) {
          float p = __expf(s[nt][r]);
          lrow[mt][r] += p;
          int row = quad * 4 + r;
          int ch = nt * 2 + (c16 >> 3);
          Pt[wave][row][((ch ^ (row & 7)) * 8) + (c16 & 7)] = (short)f2bf(p);
        }
      __builtin_amdgcn_s_setprio(1);
#pragma unroll
      for (int ks2 = 0; ks2 < 2; ++ks2) {
        short8 pf = *(const short8*)&Pt[wave][c16][(((ks2 * 4 + quad) ^ (c16 & 7)) & 7) * 8];
#pragma unroll
        for (int nt = 0; nt < 4; ++nt)
          accO[mt][nt] = __builtin_amdgcn_mfma_f32_16x16x32_bf16(pf, vbreg[ks2][nt], accO[mt][nt], 0, 0, 0);
      }
      __builtin_amdgcn_s_setprio(0);
    }
    __syncthreads();  // drains K and V DMA; protects buffer reuse
  }

  // one deferred l-reduction across the 16 c16 lanes
#pragma unroll
  for (int d = 1; d < 16; d <<= 1)
#pragma unroll
    for (int mt = 0; mt < 2; ++mt)
#pragma unroll
      for (int r = 0; r < 4; ++r) lrow[mt][r] += __shfl_xor(lrow[mt][r], d, 64);

#pragma unroll
  for (int mt = 0; mt < 2; ++mt)
#pragma unroll
    for (int nt = 0; nt < 4; ++nt)
#pragma unroll
      for (int r = 0; r < 4; ++r) {
        int qrow = qt * 128 + wave * 32 + mt * 16 + quad * 4 + r;
        O[((size_t)(b * SEQ + qrow)) * 1024 + h * 64 + nt * 16 + c16] =
            __float2bfloat16(accO[mt][nt][r] / lrow[mt][r]);
      }
#undef STAGE_K
#undef STAGE_V
}

extern "C" void kernel_launch(void* const* d_in, const int* in_sizes, int n_in,
                              void* d_out, int out_size, void* d_ws, size_t ws_size,
                              hipStream_t stream) {
  const void* q = d_in[0];
  const void* k = d_in[1];
  const void* v = d_in[2];
  const void* Wq = d_in[3];
  const void* bq = d_in[4];
  const void* Wk = d_in[5];
  const void* bk = d_in[6];
  const void* Wv = d_in[7];
  const void* bv = d_in[8];
  const void* Uq = d_in[9];
  const void* buq = d_in[10];
  const void* Uk = d_in[11];
  const void* buk = d_in[12];
  const void* pos = d_in[13];
  const void* th_cc = d_in[14];
  const void* th_co = d_in[15];
  const void* th_oc = d_in[16];
  const void* Wo = d_in[17];
  const void* bo = d_in[18];

  const int M = BS;  // 4096
  const size_t DD = (size_t)D_MODEL * D_MODEL;
  char* wsb = (char*)d_ws;
  int* flag = (int*)wsb;
  bf16* Qc = (bf16*)(wsb + 256);            // 8 MB
  bf16* Kc = Qc + (size_t)M * D_MODEL;      // 8 MB
  bf16* VcT = Kc + (size_t)M * D_MODEL;     // 8 MB, [D_MODEL][M]
  bf16* Qp = VcT + (size_t)M * D_MODEL;     // 2 MB
  bf16* Kp = Qp + (size_t)SEQ * D_MODEL;    // 2 MB
  u16* WT = (u16*)(Kp + (size_t)SEQ * D_MODEL);  // 6 x 2 MB
  bf16* AO = (bf16*)WT;  // aliases WqT..UqT (dead after g1); WoT (slot 5) untouched
  u16* Qb = WT + 6 * DD;                    // 8 MB bf16 copies of activations
  u16* Kb = Qb + (size_t)M * D_MODEL;       // 8 MB
  u16* Vb = Kb + (size_t)M * D_MODEL;       // 8 MB
  u16* Pb = Vb + (size_t)M * D_MODEL;       // 2 MB (first SEQ rows of pos_table)

  prep<<<dim3(1024, 1, 10), dim3(256), 0, stream>>>(q, k, v, pos, Wq, Wk, Wv, Uq, Uk, Wo,
                                                    Qb, Kb, Vb, Pb, WT, flag);

  GArgs g1 = {{Qb, Kb, Vb, Pb, Pb},
              {WT + 0 * DD, WT + 1 * DD, WT + 2 * DD, WT + 3 * DD, WT + 4 * DD},
              {bq, bk, bv, buq, buk},
              {Qc, Kc, VcT, Qp, Kp},
              {M, M, M, SEQ, SEQ},
              {1, 1, 2, 1, 1}};
  gemm_big<<<dim3(4, 16, 5), dim3(512), 0, stream>>>(g1, flag);

  flash_attn<<<dim3(NUM_HEADS, BATCH, SEQ / 128), dim3(256), 0, stream>>>(
      Qc, Kc, VcT, Qp, Kp, th_cc, th_co, th_oc, AO, flag);

  GArgs g2 = {{(const u16*)AO, (const u16*)AO, (const u16*)AO, (const u16*)AO, (const u16*)AO},
              {WT + 5 * DD, WT + 5 * DD, WT + 5 * DD, WT + 5 * DD, WT + 5 * DD},
              {bo, bo, bo, bo, bo},
              {d_out, d_out, d_out, d_out, d_out},
              {M, M, M, M, M},
              {0, 0, 0, 0, 0}};
  gemm_128<<<dim3(8, 32, 1), dim3(512), 0, stream>>>(g2, flag);
}